// Round 8
// baseline (184.813 us; speedup 1.0000x reference)
//
#include <hip/hip_runtime.h>
#include <hip/hip_fp16.h>

#define B_ 16
#define XL_ 1024
#define KL_ 512
#define D_ 1024
#define NEGC (-10000000.0f)

typedef _Float16 f16x8 __attribute__((ext_vector_type(8)));
typedef float f32x4 __attribute__((ext_vector_type(4)));
typedef unsigned short u16x8 __attribute__((ext_vector_type(8)));
typedef unsigned short u16x4 __attribute__((ext_vector_type(4)));

__device__ __forceinline__ unsigned short f2h(float f) {
  __half h = __float2half(f);
  return __half_as_ushort(h);
}

// ---------- build fragment-order K arrays + klog (atomic halves) ----------
__global__ __launch_bounds__(256) void k_build(const float* __restrict__ key,
    const float* __restrict__ w_key, unsigned short* __restrict__ KQ2,
    unsigned short* __restrict__ KV2, float* __restrict__ klog) {
  __shared__ unsigned short tile[64][72];
  int bid = blockIdx.x;
  int b = bid >> 4;
  int ks = (bid >> 1) & 7;
  int dh = bid & 1;
  int tid = threadIdx.x;
  int kr = tid >> 2;          // local k-row 0..63
  int cq = tid & 3;           // col quarter
  const float* krow = key + ((size_t)(b * KL_ + ks * 64 + kr)) * D_;
  float klacc = 0.f;
  int dl = tid & 63, g = tid >> 6;

  for (int dt = dh * 8; dt < dh * 8 + 8; ++dt) {
#pragma unroll
    for (int j = 0; j < 4; ++j) {
      int c = dt * 64 + cq * 16 + j * 4;
      float4 v = *(const float4*)(krow + c);
      float4 w = *(const float4*)(w_key + c);
      klacc += v.x * w.x + v.y * w.y + v.z * w.z + v.w * w.w;
      u16x4 hv;
      hv[0] = f2h(v.x); hv[1] = f2h(v.y); hv[2] = f2h(v.z); hv[3] = f2h(v.w);
      *(u16x4*)(&tile[kr][cq * 16 + j * 4]) = hv;
    }
    __syncthreads();
#pragma unroll
    for (int dkc_l = 0; dkc_l < 2; ++dkc_l) {
      u16x8 hv = *(const u16x8*)(&tile[kr][dkc_l * 32 + cq * 8]);
      size_t dst = (((size_t)(b * 8 + ks) * 32 + (dt * 2 + dkc_l)) << 11)
                   + (size_t)(((kr >> 4) & 3) * 512 + (cq * 16 + (kr & 15)) * 8);
      *(u16x8*)(KQ2 + dst) = hv;
    }
    {
      int dglob = dt * 64 + dl;
      int wv_ = dglob >> 7, np = (dglob >> 4) & 7, l15v = dglob & 15;
#pragma unroll
      for (int kkc_l = 0; kkc_l < 2; ++kkc_l) {
        u16x8 hv;
#pragma unroll
        for (int h = 0; h < 8; ++h) hv[h] = tile[kkc_l * 32 + g * 8 + h][dl];
        size_t dst = (((size_t)(b * 8 + wv_) * 16 + (ks * 2 + kkc_l)) << 12)
                     + (size_t)(np * 512 + (g * 16 + l15v) * 8);
        *(u16x8*)(KV2 + dst) = hv;
      }
    }
    __syncthreads();
  }
  klacc += __shfl_xor(klacc, 1);
  klacc += __shfl_xor(klacc, 2);
  if (cq == 0) atomicAdd(&klog[b * KL_ + ks * 64 + kr], klacc);
}

// ---------- main attention kernel ----------
// 512 thr (8 waves), 64 x-rows x KL=512 per block, 256 blocks (1/CU).
// Halves per-batch KQ2/KV2 L2 re-reads and doubles MFMA:load issue ratio
// vs the 32-row version. Epilogue does all out stores (incl. x copy).
__global__ __launch_bounds__(512, 2) void k_attn(
    const float* __restrict__ x, const float* __restrict__ x_mask,
    const float* __restrict__ key_mask, const float* __restrict__ dot_w,
    const float* __restrict__ w_input,
    const unsigned short* __restrict__ KQ2, const unsigned short* __restrict__ KV2,
    const float* __restrict__ klog,
    float* __restrict__ maxs, float* __restrict__ out) {
  __shared__ unsigned short Qall[64 * 1024];        // 128KB
  __shared__ float xlg[64];                         // fused x_logits
  unsigned short* Pt = Qall;                        // alias: 64KB P tile
  float* redA = (float*)((char*)Qall + 65536);      // aliases dead upper Q half
  float* redB = redA + 512;
  float* redC = redB + 512;

  const int tid = threadIdx.x;
  const int wv = tid >> 6;
  const int lane = tid & 63;
  const int l15 = lane & 15, l4 = lane >> 4;
  const int r7 = l15 & 7;

  int bid = blockIdx.x;
  int b = (bid & 7) * 2 + (bid >> 7);
  int x0 = ((bid >> 3) & 15) * 64;

  const float* xB = x + ((size_t)b * XL_ + x0) * D_;

  // ---- stage Q = fp16(x * dot_w), [64][1024], XOR swizzle; fused x_logits ----
  {
    int row = tid >> 3;                  // 0..63
    int cg = tid & 7;
    const float* sp = xB + (size_t)row * D_;
    char* qrow = (char*)Qall + row * 2048;
    int rsw = row & 7;
    float xl = 0.f;
#pragma unroll
    for (int j = 0; j < 32; ++j) {
      int c4 = cg + j * 8;               // f32x4 index 0..255
      f32x4 v = *(const f32x4*)(sp + c4 * 4);
      f32x4 w = *(const f32x4*)(dot_w + c4 * 4);
      f32x4 wi = *(const f32x4*)(w_input + c4 * 4);
      xl += v[0] * wi[0] + v[1] * wi[1] + v[2] * wi[2] + v[3] * wi[3];
      u16x4 hv;
      hv[0] = f2h(v[0] * w[0]); hv[1] = f2h(v[1] * w[1]);
      hv[2] = f2h(v[2] * w[2]); hv[3] = f2h(v[3] * w[3]);
      *(u16x4*)(qrow + (((c4 >> 1) ^ rsw) << 4) + ((c4 & 1) << 3)) = hv;
    }
    xl += __shfl_xor(xl, 1);
    xl += __shfl_xor(xl, 2);
    xl += __shfl_xor(xl, 4);
    if (cg == 0) xlg[row] = xl;
  }
  __syncthreads();

  // ---- QK^T: acc[m][n] = mfma(Kfrag_n, Qfrag_m), dense KQ2 loads ----
  f32x4 acc[4][4];
#pragma unroll
  for (int m = 0; m < 4; ++m)
#pragma unroll
    for (int n = 0; n < 4; ++n) { f32x4 z = {0.f, 0.f, 0.f, 0.f}; acc[m][n] = z; }

  const unsigned short* KQ2w = KQ2 + (((size_t)(b * 8 + wv) * 32) << 11) + lane * 8;
  const char* qa0 = (char*)Qall + l15 * 2048;
  const char* qa1 = (char*)Qall + (16 + l15) * 2048;
  const char* qa2 = (char*)Qall + (32 + l15) * 2048;
  const char* qa3 = (char*)Qall + (48 + l15) * 2048;

#pragma unroll 2
  for (int dk = 0; dk < D_; dk += 32) {
    const unsigned short* cp = KQ2w + ((dk >> 5) << 11);
    f16x8 b0 = *(const f16x8*)(cp);
    f16x8 b1 = *(const f16x8*)(cp + 512);
    f16x8 b2 = *(const f16x8*)(cp + 1024);
    f16x8 b3 = *(const f16x8*)(cp + 1536);
    int c = (((dk >> 3) + l4) ^ r7) << 4;
    f16x8 a0 = *(const f16x8*)(qa0 + c);
    f16x8 a1 = *(const f16x8*)(qa1 + c);
    f16x8 a2 = *(const f16x8*)(qa2 + c);
    f16x8 a3 = *(const f16x8*)(qa3 + c);
    __builtin_amdgcn_s_setprio(1);
    acc[0][0] = __builtin_amdgcn_mfma_f32_16x16x32_f16(b0, a0, acc[0][0], 0, 0, 0);
    acc[1][0] = __builtin_amdgcn_mfma_f32_16x16x32_f16(b0, a1, acc[1][0], 0, 0, 0);
    acc[2][0] = __builtin_amdgcn_mfma_f32_16x16x32_f16(b0, a2, acc[2][0], 0, 0, 0);
    acc[3][0] = __builtin_amdgcn_mfma_f32_16x16x32_f16(b0, a3, acc[3][0], 0, 0, 0);
    acc[0][1] = __builtin_amdgcn_mfma_f32_16x16x32_f16(b1, a0, acc[0][1], 0, 0, 0);
    acc[1][1] = __builtin_amdgcn_mfma_f32_16x16x32_f16(b1, a1, acc[1][1], 0, 0, 0);
    acc[2][1] = __builtin_amdgcn_mfma_f32_16x16x32_f16(b1, a2, acc[2][1], 0, 0, 0);
    acc[3][1] = __builtin_amdgcn_mfma_f32_16x16x32_f16(b1, a3, acc[3][1], 0, 0, 0);
    acc[0][2] = __builtin_amdgcn_mfma_f32_16x16x32_f16(b2, a0, acc[0][2], 0, 0, 0);
    acc[1][2] = __builtin_amdgcn_mfma_f32_16x16x32_f16(b2, a1, acc[1][2], 0, 0, 0);
    acc[2][2] = __builtin_amdgcn_mfma_f32_16x16x32_f16(b2, a2, acc[2][2], 0, 0, 0);
    acc[3][2] = __builtin_amdgcn_mfma_f32_16x16x32_f16(b2, a3, acc[3][2], 0, 0, 0);
    acc[0][3] = __builtin_amdgcn_mfma_f32_16x16x32_f16(b3, a0, acc[0][3], 0, 0, 0);
    acc[1][3] = __builtin_amdgcn_mfma_f32_16x16x32_f16(b3, a1, acc[1][3], 0, 0, 0);
    acc[2][3] = __builtin_amdgcn_mfma_f32_16x16x32_f16(b3, a2, acc[2][3], 0, 0, 0);
    acc[3][3] = __builtin_amdgcn_mfma_f32_16x16x32_f16(b3, a3, acc[3][3], 0, 0, 0);
    __builtin_amdgcn_s_setprio(0);
  }
  __syncthreads();   // Q region dead beyond this point

  // ---- softmax over KL ----
  float xlv[4], xmv[4];
#pragma unroll
  for (int m = 0; m < 4; ++m) {
    int row = m * 16 + l15;
    xlv[m] = xlg[row];
    xmv[m] = x_mask[(size_t)b * XL_ + x0 + row];
  }
  f32x4 klv[4], kmv[4];
#pragma unroll
  for (int n = 0; n < 4; ++n) {
    int kb = wv * 64 + n * 16 + l4 * 4;
    klv[n] = *(const f32x4*)(klog + (size_t)b * KL_ + kb);
    kmv[n] = *(const f32x4*)(key_mask + (size_t)b * KL_ + kb);
  }
  float mxsm[4], mxs2[4];
#pragma unroll
  for (int m = 0; m < 4; ++m) { mxsm[m] = -3.0e38f; mxs2[m] = -3.0e38f; }
#pragma unroll
  for (int m = 0; m < 4; ++m)
#pragma unroll
    for (int n = 0; n < 4; ++n)
#pragma unroll
      for (int q = 0; q < 4; ++q) {
        float s = acc[m][n][q] + xlv[m] + klv[n][q];
        float sm = s + (1.f - xmv[m] * kmv[n][q]) * NEGC;
        float s2 = s * kmv[n][q] + (1.f - kmv[n][q]) * NEGC;
        mxsm[m] = fmaxf(mxsm[m], sm);
        mxs2[m] = fmaxf(mxs2[m], s2);
      }
#pragma unroll
  for (int m = 0; m < 4; ++m) {
    mxsm[m] = fmaxf(mxsm[m], __shfl_xor(mxsm[m], 16));
    mxsm[m] = fmaxf(mxsm[m], __shfl_xor(mxsm[m], 32));
    mxs2[m] = fmaxf(mxs2[m], __shfl_xor(mxs2[m], 16));
    mxs2[m] = fmaxf(mxs2[m], __shfl_xor(mxs2[m], 32));
  }
  if (l4 == 0) {
#pragma unroll
    for (int m = 0; m < 4; ++m) {
      redA[wv * 64 + m * 16 + l15] = mxsm[m];
      redB[wv * 64 + m * 16 + l15] = mxs2[m];
    }
  }
  __syncthreads();
  float gmx[4];
#pragma unroll
  for (int m = 0; m < 4; ++m) {
    int row = m * 16 + l15;
    float v = redA[row];
#pragma unroll
    for (int w = 1; w < 8; ++w) v = fmaxf(v, redA[w * 64 + row]);
    gmx[m] = v;
  }
  if (tid < 64) {
    float v = redB[tid];
#pragma unroll
    for (int w = 1; w < 8; ++w) v = fmaxf(v, redB[w * 64 + tid]);
    maxs[(size_t)b * XL_ + x0 + tid] = v;
  }
  // exp pass: P^ written as [x-row][k] fp16, 8B granules, XOR-swizzled
  float rs[4] = {0.f, 0.f, 0.f, 0.f};
#pragma unroll
  for (int m = 0; m < 4; ++m) {
    int row = m * 16 + l15;
    char* prow = (char*)Pt + row * 1024;
    int rsw = row & 7;
#pragma unroll
    for (int n = 0; n < 4; ++n) {
      int k = wv * 64 + n * 16 + l4 * 4;
      u16x4 pk;
#pragma unroll
      for (int q = 0; q < 4; ++q) {
        float s = acc[m][n][q] + xlv[m] + klv[n][q];
        float sm = s + (1.f - xmv[m] * kmv[n][q]) * NEGC;
        float e = __expf(sm - gmx[m]);
        rs[m] += e;
        pk[q] = f2h(e);
      }
      *(u16x4*)(prow + ((((k >> 3) ^ rsw) << 4) + ((k & 4) << 1))) = pk;
    }
  }
#pragma unroll
  for (int m = 0; m < 4; ++m) {
    rs[m] += __shfl_xor(rs[m], 16);
    rs[m] += __shfl_xor(rs[m], 32);
  }
  if (l4 == 0) {
#pragma unroll
    for (int m = 0; m < 4; ++m) redC[wv * 64 + m * 16 + l15] = rs[m];
  }
  __syncthreads();

  // ---- PV: acc2[m][n] = mfma(KhTfrag_n, Pfrag_m), dense KV2 loads ----
  float dn[4];
#pragma unroll
  for (int m = 0; m < 4; ++m) {
    int row = m * 16 + l15;
    float sum = redC[row];
#pragma unroll
    for (int w = 1; w < 8; ++w) sum += redC[w * 64 + row];
    dn[m] = 1.f / sum;
  }
  size_t obase0 = ((size_t)b * XL_ + x0) * (size_t)(4 * D_);
  const char* pa0 = (char*)Pt + l15 * 1024;
  const char* pa1 = (char*)Pt + (16 + l15) * 1024;
  const char* pa2 = (char*)Pt + (32 + l15) * 1024;
  const char* pa3 = (char*)Pt + (48 + l15) * 1024;
  const unsigned short* KV2w = KV2 + (((size_t)(b * 8 + wv) * 16) << 12) + lane * 8;
#pragma unroll
  for (int sc = 0; sc < 2; ++sc) {
    int c0 = wv * 128 + sc * 64;
    f32x4 acc2[4][4];
#pragma unroll
    for (int m = 0; m < 4; ++m)
#pragma unroll
      for (int n = 0; n < 4; ++n) { f32x4 z = {0.f, 0.f, 0.f, 0.f}; acc2[m][n] = z; }
    const unsigned short* KV2s = KV2w + sc * 4 * 512;
#pragma unroll 2
    for (int kk = 0; kk < KL_; kk += 32) {
      const unsigned short* cp = KV2s + ((kk >> 5) << 12);
      f16x8 b0 = *(const f16x8*)(cp);
      f16x8 b1 = *(const f16x8*)(cp + 512);
      f16x8 b2 = *(const f16x8*)(cp + 1024);
      f16x8 b3 = *(const f16x8*)(cp + 1536);
      int c = ((((kk >> 3) + l4) ^ r7) << 4);
      f16x8 a0 = *(const f16x8*)(pa0 + c);
      f16x8 a1 = *(const f16x8*)(pa1 + c);
      f16x8 a2 = *(const f16x8*)(pa2 + c);
      f16x8 a3 = *(const f16x8*)(pa3 + c);
      __builtin_amdgcn_s_setprio(1);
      acc2[0][0] = __builtin_amdgcn_mfma_f32_16x16x32_f16(b0, a0, acc2[0][0], 0, 0, 0);
      acc2[1][0] = __builtin_amdgcn_mfma_f32_16x16x32_f16(b0, a1, acc2[1][0], 0, 0, 0);
      acc2[2][0] = __builtin_amdgcn_mfma_f32_16x16x32_f16(b0, a2, acc2[2][0], 0, 0, 0);
      acc2[3][0] = __builtin_amdgcn_mfma_f32_16x16x32_f16(b0, a3, acc2[3][0], 0, 0, 0);
      acc2[0][1] = __builtin_amdgcn_mfma_f32_16x16x32_f16(b1, a0, acc2[0][1], 0, 0, 0);
      acc2[1][1] = __builtin_amdgcn_mfma_f32_16x16x32_f16(b1, a1, acc2[1][1], 0, 0, 0);
      acc2[2][1] = __builtin_amdgcn_mfma_f32_16x16x32_f16(b1, a2, acc2[2][1], 0, 0, 0);
      acc2[3][1] = __builtin_amdgcn_mfma_f32_16x16x32_f16(b1, a3, acc2[3][1], 0, 0, 0);
      acc2[0][2] = __builtin_amdgcn_mfma_f32_16x16x32_f16(b2, a0, acc2[0][2], 0, 0, 0);
      acc2[1][2] = __builtin_amdgcn_mfma_f32_16x16x32_f16(b2, a1, acc2[1][2], 0, 0, 0);
      acc2[2][2] = __builtin_amdgcn_mfma_f32_16x16x32_f16(b2, a2, acc2[2][2], 0, 0, 0);
      acc2[3][2] = __builtin_amdgcn_mfma_f32_16x16x32_f16(b2, a3, acc2[3][2], 0, 0, 0);
      acc2[0][3] = __builtin_amdgcn_mfma_f32_16x16x32_f16(b3, a0, acc2[0][3], 0, 0, 0);
      acc2[1][3] = __builtin_amdgcn_mfma_f32_16x16x32_f16(b3, a1, acc2[1][3], 0, 0, 0);
      acc2[2][3] = __builtin_amdgcn_mfma_f32_16x16x32_f16(b3, a2, acc2[2][3], 0, 0, 0);
      acc2[3][3] = __builtin_amdgcn_mfma_f32_16x16x32_f16(b3, a3, acc2[3][3], 0, 0, 0);
      __builtin_amdgcn_s_setprio(0);
    }
#pragma unroll
    for (int m = 0; m < 4; ++m) {
      int row = m * 16 + l15;
      size_t ob = obase0 + (size_t)row * (4 * D_);
      const float* xr = xB + (size_t)row * D_;
#pragma unroll
      for (int n = 0; n < 4; ++n) {
        int col = c0 + n * 16 + l4 * 4;
        f32x4 v = acc2[m][n];
        v[0] *= dn[m]; v[1] *= dn[m]; v[2] *= dn[m]; v[3] *= dn[m];
        f32x4 xv = *(const f32x4*)(xr + col);
        *(f32x4*)(out + ob + col) = xv;                 // out[:,0:D) = x
        *(f32x4*)(out + ob + D_ + col) = v;             // x2key
        f32x4 pv;
        pv[0] = v[0] * xv[0]; pv[1] = v[1] * xv[1];
        pv[2] = v[2] * xv[2]; pv[3] = v[3] * xv[3];
        *(f32x4*)(out + ob + 2 * D_ + col) = pv;        // x * x2key
      }
    }
  }
}

// ---------- key2x partials with fused p-softmax: block (b, xc) ----------
__global__ __launch_bounds__(256) void k_key2x_part(const float* __restrict__ x,
    const float* __restrict__ maxs, const float* __restrict__ x_mask,
    float* __restrict__ partial) {
  int b = blockIdx.x >> 4;
  int xc = blockIdx.x & 15;
  int tid = threadIdx.x;
  int wvi = tid >> 6, lane = tid & 63;
  __shared__ float r1[4], r2[4], r3[4];
  __shared__ float ps_all[XL_];
  const float* ms = maxs + (size_t)b * XL_;
  const float* xm = x_mask + (size_t)b * XL_;
  float tv[4], xmv[4];
  float vmax = -3.0e38f;
#pragma unroll
  for (int i = 0; i < 4; ++i) {
    int xi = i * 256 + tid;
    xmv[i] = xm[xi];
    tv[i] = ms[xi] * xmv[i];
    vmax = fmaxf(vmax, tv[i]);
  }
#pragma unroll
  for (int sh = 32; sh >= 1; sh >>= 1) vmax = fmaxf(vmax, __shfl_xor(vmax, sh));
  if (lane == 0) r1[wvi] = vmax;
  __syncthreads();
  float gmax = fmaxf(fmaxf(r1[0], r1[1]), fmaxf(r1[2], r1[3]));
  float e[4]; float es = 0.f;
#pragma unroll
  for (int i = 0; i < 4; ++i) { e[i] = __expf(tv[i] - gmax); es += e[i]; }
#pragma unroll
  for (int sh = 32; sh >= 1; sh >>= 1) es += __shfl_xor(es, sh);
  if (lane == 0) r2[wvi] = es;
  __syncthreads();
  float gsum = r2[0] + r2[1] + r2[2] + r2[3];
  float pv4[4]; float psum = 0.f;
#pragma unroll
  for (int i = 0; i < 4; ++i) { pv4[i] = e[i] / gsum * xmv[i]; psum += pv4[i]; }
#pragma unroll
  for (int sh = 32; sh >= 1; sh >>= 1) psum += __shfl_xor(psum, sh);
  if (lane == 0) r3[wvi] = psum;
  __syncthreads();
  float gps = r3[0] + r3[1] + r3[2] + r3[3];
  float inv = 1.f / (gps + 1e-13f);
#pragma unroll
  for (int i = 0; i < 4; ++i) ps_all[i * 256 + tid] = pv4[i] * inv;
  __syncthreads();
  const float* xb = x + ((size_t)b * XL_ + xc * 64) * D_;
  float acc0 = 0.f, acc1 = 0.f, acc2 = 0.f, acc3 = 0.f;
  int d = tid;
  const float* psl = ps_all + xc * 64;
  for (int xi = 0; xi < 64; ++xi) {
    float pv = psl[xi];
    const float* rp = xb + (size_t)xi * D_;
    acc0 += pv * __builtin_nontemporal_load(rp + d);
    acc1 += pv * __builtin_nontemporal_load(rp + d + 256);
    acc2 += pv * __builtin_nontemporal_load(rp + d + 512);
    acc3 += pv * __builtin_nontemporal_load(rp + d + 768);
  }
  float* pp = partial + (size_t)blockIdx.x * D_;
  pp[d] = acc0; pp[d + 256] = acc1; pp[d + 512] = acc2; pp[d + 768] = acc3;
}

// ---------- key2x reduce: k2x[b][d] = sum_xc partial ----------
__global__ __launch_bounds__(256) void k_key2x_red(const float* __restrict__ partial,
    float* __restrict__ k2x) {
  int idx = blockIdx.x * 256 + threadIdx.x;
  int b = idx >> 10;
  float s = 0.f;
#pragma unroll
  for (int xc = 0; xc < 16; ++xc)
    s += partial[((size_t)b * 16 + xc) * D_ + (idx & 1023)];
  k2x[idx] = s;
}

// ---------- out[.,3D:4D) = x * key2x ----------
__global__ __launch_bounds__(256) void k_outfinal(const float* __restrict__ x,
    const float* __restrict__ k2x, float* __restrict__ out) {
  size_t t = (size_t)blockIdx.x * 256 + threadIdx.x;
  size_t base = t * 4;
  int b = (int)(base >> 20);
  int rem = (int)(base & ((1u << 20) - 1));
  int xr = rem >> 10;
  int d = rem & 1023;
  f32x4 xv = __builtin_nontemporal_load((const f32x4*)(x + base));
  f32x4 kv = *(const f32x4*)(k2x + (size_t)b * D_ + d);
  float* orow = out + ((size_t)b * XL_ + xr) * (size_t)(4 * D_);
  f32x4 pr;
  pr[0] = xv[0] * kv[0]; pr[1] = xv[1] * kv[1];
  pr[2] = xv[2] * kv[2]; pr[3] = xv[3] * kv[3];
  __builtin_nontemporal_store(pr, (f32x4*)(orow + 3 * D_ + d));
}

extern "C" void kernel_launch(void* const* d_in, const int* in_sizes, int n_in,
                              void* d_out, int out_size, void* d_ws, size_t ws_size,
                              hipStream_t stream) {
  (void)in_sizes; (void)n_in; (void)out_size; (void)ws_size;
  const float* x        = (const float*)d_in[0];
  const float* x_mask   = (const float*)d_in[1];
  const float* key      = (const float*)d_in[2];
  const float* key_mask = (const float*)d_in[3];
  const float* w_input  = (const float*)d_in[4];
  const float* w_key    = (const float*)d_in[5];
  const float* dot_w    = (const float*)d_in[6];
  float* out = (float*)d_out;
  char* ws = (char*)d_ws;

  unsigned short* KQ2 = (unsigned short*)ws;                        // 16 MB
  unsigned short* KV2 = (unsigned short*)(ws + (16u << 20));        // 16 MB
  float* xlog = (float*)(ws + (32u << 20));                         // 64 KB (unused)
  float* klog = xlog + B_ * XL_;                                    // 32 KB
  float* maxs = klog + B_ * KL_;                                    // 64 KB
  float* pbuf = maxs + B_ * XL_;                                    // 64 KB (unused)
  float* k2x  = pbuf + B_ * XL_;                                    // 64 KB
  float* partial = (float*)ws;   // 1 MB, aliases KQ2 (dead after k_attn)

  hipMemsetAsync(klog, 0, B_ * KL_ * sizeof(float), stream);
  k_build<<<dim3(B_ * 16), dim3(256), 0, stream>>>(key, w_key, KQ2, KV2, klog);
  k_attn<<<dim3(256), dim3(512), 0, stream>>>(x, x_mask, key_mask, dot_w, w_input,
                                              KQ2, KV2, klog, maxs, out);
  k_key2x_part<<<dim3(B_ * 16), dim3(256), 0, stream>>>(x, maxs, x_mask, partial);
  k_key2x_red<<<dim3(B_ * D_ / 256), dim3(256), 0, stream>>>(partial, k2x);
  k_outfinal<<<dim3(B_ * XL_ * D_ / 1024), dim3(256), 0, stream>>>(x, k2x, out);
}

// Round 9
// 169.140 us; speedup vs baseline: 1.0927x; 1.0927x over previous
//
#include <hip/hip_runtime.h>
#include <hip/hip_fp16.h>

#define B_ 16
#define XL_ 1024
#define KL_ 512
#define D_ 1024
#define NEGC (-10000000.0f)

typedef _Float16 f16x8 __attribute__((ext_vector_type(8)));
typedef float f32x4 __attribute__((ext_vector_type(4)));
typedef unsigned short u16x8 __attribute__((ext_vector_type(8)));
typedef unsigned short u16x4 __attribute__((ext_vector_type(4)));

__device__ __forceinline__ unsigned short f2h(float f) {
  __half h = __float2half(f);
  return __half_as_ushort(h);
}

// ---------- build fragment-order K arrays + klog (atomic halves) ----------
__global__ __launch_bounds__(256) void k_build(const float* __restrict__ key,
    const float* __restrict__ w_key, unsigned short* __restrict__ KQ2,
    unsigned short* __restrict__ KV2, float* __restrict__ klog) {
  __shared__ unsigned short tile[64][72];
  int bid = blockIdx.x;
  int b = bid >> 4;
  int ks = (bid >> 1) & 7;
  int dh = bid & 1;
  int tid = threadIdx.x;
  int kr = tid >> 2;          // local k-row 0..63
  int cq = tid & 3;           // col quarter
  const float* krow = key + ((size_t)(b * KL_ + ks * 64 + kr)) * D_;
  float klacc = 0.f;
  int dl = tid & 63, g = tid >> 6;

  for (int dt = dh * 8; dt < dh * 8 + 8; ++dt) {
#pragma unroll
    for (int j = 0; j < 4; ++j) {
      int c = dt * 64 + cq * 16 + j * 4;
      f32x4 v = __builtin_nontemporal_load((const f32x4*)(krow + c));
      f32x4 w = *(const f32x4*)(w_key + c);
      klacc += v[0] * w[0] + v[1] * w[1] + v[2] * w[2] + v[3] * w[3];
      u16x4 hv;
      hv[0] = f2h(v[0]); hv[1] = f2h(v[1]); hv[2] = f2h(v[2]); hv[3] = f2h(v[3]);
      *(u16x4*)(&tile[kr][cq * 16 + j * 4]) = hv;
    }
    __syncthreads();
#pragma unroll
    for (int dkc_l = 0; dkc_l < 2; ++dkc_l) {
      u16x8 hv = *(const u16x8*)(&tile[kr][dkc_l * 32 + cq * 8]);
      size_t dst = (((size_t)(b * 8 + ks) * 32 + (dt * 2 + dkc_l)) << 11)
                   + (size_t)(((kr >> 4) & 3) * 512 + (cq * 16 + (kr & 15)) * 8);
      *(u16x8*)(KQ2 + dst) = hv;
    }
    {
      int dglob = dt * 64 + dl;
      int wv_ = dglob >> 7, np = (dglob >> 4) & 7, l15v = dglob & 15;
#pragma unroll
      for (int kkc_l = 0; kkc_l < 2; ++kkc_l) {
        u16x8 hv;
#pragma unroll
        for (int h = 0; h < 8; ++h) hv[h] = tile[kkc_l * 32 + g * 8 + h][dl];
        size_t dst = (((size_t)(b * 8 + wv_) * 16 + (ks * 2 + kkc_l)) << 12)
                     + (size_t)(np * 512 + (g * 16 + l15v) * 8);
        *(u16x8*)(KV2 + dst) = hv;
      }
    }
    __syncthreads();
  }
  klacc += __shfl_xor(klacc, 1);
  klacc += __shfl_xor(klacc, 2);
  if (cq == 0) atomicAdd(&klog[b * KL_ + ks * 64 + kr], klacc);
}

// ---------- main attention kernel ----------
// R6 structure: 512 thr (8 waves), 32 x-rows x KL=512, 512 blocks (2/CU).
// Dense fragment-order K loads; x_logits fused into Q staging.
// Epilogue writes ONLY x2key -> out[:,D:2D) (nt). All other out segments
// are produced by the streaming k_mega kernel (traffic moved, not added).
__global__ __launch_bounds__(512, 4) void k_attn(
    const float* __restrict__ x, const float* __restrict__ x_mask,
    const float* __restrict__ key_mask, const float* __restrict__ dot_w,
    const float* __restrict__ w_input,
    const unsigned short* __restrict__ KQ2, const unsigned short* __restrict__ KV2,
    const float* __restrict__ klog,
    float* __restrict__ maxs, float* __restrict__ out) {
  __shared__ unsigned short Qall[32 * 1024];        // 64KB
  __shared__ float xlg[32];                         // fused x_logits
  unsigned short* Pt = Qall;                        // alias: 32KB P tile
  float* redA = (float*)(Qall + 16384);             // byte 32768+
  float* redB = redA + 256;
  float* redC = redB + 256;

  const int tid = threadIdx.x;
  const int wv = tid >> 6;
  const int lane = tid & 63;
  const int l15 = lane & 15, l4 = lane >> 4;
  const int r7 = l15 & 7;

  int bid = blockIdx.x;
  int b = (bid & 7) * 2 + (bid >> 8);
  int x0 = ((bid >> 3) & 31) * 32;

  const float* xB = x + ((size_t)b * XL_ + x0) * D_;

  // ---- stage Q = fp16(x * dot_w); fused x_logits ----
  {
    int row = tid >> 4;
    int cg = tid & 15;
    const float* sp = xB + (size_t)row * D_;
    char* qrow = (char*)Qall + row * 2048;
    int rsw = row & 7;
    float xl = 0.f;
#pragma unroll
    for (int j = 0; j < 16; ++j) {
      int c4 = cg + j * 16;
      f32x4 v = *(const f32x4*)(sp + c4 * 4);
      f32x4 w = *(const f32x4*)(dot_w + c4 * 4);
      f32x4 wi = *(const f32x4*)(w_input + c4 * 4);
      xl += v[0] * wi[0] + v[1] * wi[1] + v[2] * wi[2] + v[3] * wi[3];
      u16x4 hv;
      hv[0] = f2h(v[0] * w[0]); hv[1] = f2h(v[1] * w[1]);
      hv[2] = f2h(v[2] * w[2]); hv[3] = f2h(v[3] * w[3]);
      *(u16x4*)(qrow + (((c4 >> 1) ^ rsw) << 4) + ((c4 & 1) << 3)) = hv;
    }
    xl += __shfl_xor(xl, 1);
    xl += __shfl_xor(xl, 2);
    xl += __shfl_xor(xl, 4);
    xl += __shfl_xor(xl, 8);
    if (cg == 0) xlg[row] = xl;
  }
  __syncthreads();

  // ---- QK^T: acc[m][n] = mfma(Kfrag_n, Qfrag_m), dense KQ2 loads ----
  f32x4 acc[2][4];
#pragma unroll
  for (int m = 0; m < 2; ++m)
#pragma unroll
    for (int n = 0; n < 4; ++n) { f32x4 z = {0.f, 0.f, 0.f, 0.f}; acc[m][n] = z; }

  const unsigned short* KQ2w = KQ2 + (((size_t)(b * 8 + wv) * 32) << 11) + lane * 8;
  const char* qa0 = (char*)Qall + l15 * 2048;
  const char* qa1 = (char*)Qall + (16 + l15) * 2048;

#pragma unroll 4
  for (int dk = 0; dk < D_; dk += 32) {
    const unsigned short* cp = KQ2w + ((dk >> 5) << 11);
    f16x8 b0 = *(const f16x8*)(cp);
    f16x8 b1 = *(const f16x8*)(cp + 512);
    f16x8 b2 = *(const f16x8*)(cp + 1024);
    f16x8 b3 = *(const f16x8*)(cp + 1536);
    int c = (((dk >> 3) + l4) ^ r7) << 4;
    f16x8 a0 = *(const f16x8*)(qa0 + c);
    f16x8 a1 = *(const f16x8*)(qa1 + c);
    __builtin_amdgcn_s_setprio(1);
    acc[0][0] = __builtin_amdgcn_mfma_f32_16x16x32_f16(b0, a0, acc[0][0], 0, 0, 0);
    acc[1][0] = __builtin_amdgcn_mfma_f32_16x16x32_f16(b0, a1, acc[1][0], 0, 0, 0);
    acc[0][1] = __builtin_amdgcn_mfma_f32_16x16x32_f16(b1, a0, acc[0][1], 0, 0, 0);
    acc[1][1] = __builtin_amdgcn_mfma_f32_16x16x32_f16(b1, a1, acc[1][1], 0, 0, 0);
    acc[0][2] = __builtin_amdgcn_mfma_f32_16x16x32_f16(b2, a0, acc[0][2], 0, 0, 0);
    acc[1][2] = __builtin_amdgcn_mfma_f32_16x16x32_f16(b2, a1, acc[1][2], 0, 0, 0);
    acc[0][3] = __builtin_amdgcn_mfma_f32_16x16x32_f16(b3, a0, acc[0][3], 0, 0, 0);
    acc[1][3] = __builtin_amdgcn_mfma_f32_16x16x32_f16(b3, a1, acc[1][3], 0, 0, 0);
    __builtin_amdgcn_s_setprio(0);
  }
  __syncthreads();   // Q region dead beyond this point

  // ---- softmax over KL ----
  float xlv[2], xmv[2];
#pragma unroll
  for (int m = 0; m < 2; ++m) {
    int row = m * 16 + l15;
    xlv[m] = xlg[row];
    xmv[m] = x_mask[(size_t)b * XL_ + x0 + row];
  }
  f32x4 klv[4], kmv[4];
#pragma unroll
  for (int n = 0; n < 4; ++n) {
    int kb = wv * 64 + n * 16 + l4 * 4;
    klv[n] = *(const f32x4*)(klog + (size_t)b * KL_ + kb);
    kmv[n] = *(const f32x4*)(key_mask + (size_t)b * KL_ + kb);
  }
  float mxsm[2] = {-3.0e38f, -3.0e38f}, mxs2[2] = {-3.0e38f, -3.0e38f};
#pragma unroll
  for (int m = 0; m < 2; ++m)
#pragma unroll
    for (int n = 0; n < 4; ++n)
#pragma unroll
      for (int q = 0; q < 4; ++q) {
        float s = acc[m][n][q] + xlv[m] + klv[n][q];
        float sm = s + (1.f - xmv[m] * kmv[n][q]) * NEGC;
        float s2 = s * kmv[n][q] + (1.f - kmv[n][q]) * NEGC;
        mxsm[m] = fmaxf(mxsm[m], sm);
        mxs2[m] = fmaxf(mxs2[m], s2);
      }
#pragma unroll
  for (int m = 0; m < 2; ++m) {
    mxsm[m] = fmaxf(mxsm[m], __shfl_xor(mxsm[m], 16));
    mxsm[m] = fmaxf(mxsm[m], __shfl_xor(mxsm[m], 32));
    mxs2[m] = fmaxf(mxs2[m], __shfl_xor(mxs2[m], 16));
    mxs2[m] = fmaxf(mxs2[m], __shfl_xor(mxs2[m], 32));
  }
  if (l4 == 0) {
#pragma unroll
    for (int m = 0; m < 2; ++m) {
      redA[wv * 32 + m * 16 + l15] = mxsm[m];
      redB[wv * 32 + m * 16 + l15] = mxs2[m];
    }
  }
  __syncthreads();
  float gmx[2];
#pragma unroll
  for (int m = 0; m < 2; ++m) {
    int row = m * 16 + l15;
    float v = redA[row];
#pragma unroll
    for (int w = 1; w < 8; ++w) v = fmaxf(v, redA[w * 32 + row]);
    gmx[m] = v;
  }
  if (tid < 32) {
    float v = redB[tid];
#pragma unroll
    for (int w = 1; w < 8; ++w) v = fmaxf(v, redB[w * 32 + tid]);
    maxs[(size_t)b * XL_ + x0 + tid] = v;
  }
  // exp pass: P^ written as [x-row][k] fp16, 8B granules, XOR-swizzled
  float rs[2] = {0.f, 0.f};
#pragma unroll
  for (int m = 0; m < 2; ++m) {
    int row = m * 16 + l15;
    char* prow = (char*)Pt + row * 1024;
    int rsw = row & 7;
#pragma unroll
    for (int n = 0; n < 4; ++n) {
      int k = wv * 64 + n * 16 + l4 * 4;
      u16x4 pk;
#pragma unroll
      for (int q = 0; q < 4; ++q) {
        float s = acc[m][n][q] + xlv[m] + klv[n][q];
        float sm = s + (1.f - xmv[m] * kmv[n][q]) * NEGC;
        float e = __expf(sm - gmx[m]);
        rs[m] += e;
        pk[q] = f2h(e);
      }
      *(u16x4*)(prow + ((((k >> 3) ^ rsw) << 4) + ((k & 4) << 1))) = pk;
    }
  }
#pragma unroll
  for (int m = 0; m < 2; ++m) {
    rs[m] += __shfl_xor(rs[m], 16);
    rs[m] += __shfl_xor(rs[m], 32);
  }
  if (l4 == 0) {
#pragma unroll
    for (int m = 0; m < 2; ++m) redC[wv * 32 + m * 16 + l15] = rs[m];
  }
  __syncthreads();

  // ---- PV: acc2[m][n] = mfma(KhTfrag_n, Pfrag_m), dense KV2 loads ----
  float dn[2];
#pragma unroll
  for (int m = 0; m < 2; ++m) {
    int row = m * 16 + l15;
    float sum = redC[row];
#pragma unroll
    for (int w = 1; w < 8; ++w) sum += redC[w * 32 + row];
    dn[m] = 1.f / sum;
  }
  size_t obase0 = ((size_t)b * XL_ + x0) * (size_t)(4 * D_);
  const char* pa0 = (char*)Pt + l15 * 1024;
  const char* pa1 = (char*)Pt + (16 + l15) * 1024;
  const unsigned short* KV2w = KV2 + (((size_t)(b * 8 + wv) * 16) << 12) + lane * 8;
#pragma unroll
  for (int sc = 0; sc < 2; ++sc) {
    int c0 = wv * 128 + sc * 64;
    f32x4 acc2[2][4];
#pragma unroll
    for (int m = 0; m < 2; ++m)
#pragma unroll
      for (int n = 0; n < 4; ++n) { f32x4 z = {0.f, 0.f, 0.f, 0.f}; acc2[m][n] = z; }
    const unsigned short* KV2s = KV2w + sc * 4 * 512;
#pragma unroll 4
    for (int kk = 0; kk < KL_; kk += 32) {
      const unsigned short* cp = KV2s + ((kk >> 5) << 12);
      f16x8 b0 = *(const f16x8*)(cp);
      f16x8 b1 = *(const f16x8*)(cp + 512);
      f16x8 b2 = *(const f16x8*)(cp + 1024);
      f16x8 b3 = *(const f16x8*)(cp + 1536);
      int c = ((((kk >> 3) + l4) ^ r7) << 4);
      f16x8 a0 = *(const f16x8*)(pa0 + c);
      f16x8 a1 = *(const f16x8*)(pa1 + c);
      __builtin_amdgcn_s_setprio(1);
      acc2[0][0] = __builtin_amdgcn_mfma_f32_16x16x32_f16(b0, a0, acc2[0][0], 0, 0, 0);
      acc2[1][0] = __builtin_amdgcn_mfma_f32_16x16x32_f16(b0, a1, acc2[1][0], 0, 0, 0);
      acc2[0][1] = __builtin_amdgcn_mfma_f32_16x16x32_f16(b1, a0, acc2[0][1], 0, 0, 0);
      acc2[1][1] = __builtin_amdgcn_mfma_f32_16x16x32_f16(b1, a1, acc2[1][1], 0, 0, 0);
      acc2[0][2] = __builtin_amdgcn_mfma_f32_16x16x32_f16(b2, a0, acc2[0][2], 0, 0, 0);
      acc2[1][2] = __builtin_amdgcn_mfma_f32_16x16x32_f16(b2, a1, acc2[1][2], 0, 0, 0);
      acc2[0][3] = __builtin_amdgcn_mfma_f32_16x16x32_f16(b3, a0, acc2[0][3], 0, 0, 0);
      acc2[1][3] = __builtin_amdgcn_mfma_f32_16x16x32_f16(b3, a1, acc2[1][3], 0, 0, 0);
      __builtin_amdgcn_s_setprio(0);
    }
#pragma unroll
    for (int m = 0; m < 2; ++m) {
      int row = m * 16 + l15;
      size_t ob = obase0 + (size_t)row * (4 * D_);
#pragma unroll
      for (int n = 0; n < 4; ++n) {
        int col = c0 + n * 16 + l4 * 4;
        f32x4 v = acc2[m][n];
        v[0] *= dn[m]; v[1] *= dn[m]; v[2] *= dn[m]; v[3] *= dn[m];
        __builtin_nontemporal_store(v, (f32x4*)(out + ob + D_ + col));  // x2key only
      }
    }
  }
}

// ---------- key2x partials with fused p-softmax: block (b, xc) ----------
__global__ __launch_bounds__(256) void k_key2x_part(const float* __restrict__ x,
    const float* __restrict__ maxs, const float* __restrict__ x_mask,
    float* __restrict__ partial) {
  int b = blockIdx.x >> 4;
  int xc = blockIdx.x & 15;
  int tid = threadIdx.x;
  int wvi = tid >> 6, lane = tid & 63;
  __shared__ float r1[4], r2[4], r3[4];
  __shared__ float ps_all[XL_];
  const float* ms = maxs + (size_t)b * XL_;
  const float* xm = x_mask + (size_t)b * XL_;
  float tv[4], xmv[4];
  float vmax = -3.0e38f;
#pragma unroll
  for (int i = 0; i < 4; ++i) {
    int xi = i * 256 + tid;
    xmv[i] = xm[xi];
    tv[i] = ms[xi] * xmv[i];
    vmax = fmaxf(vmax, tv[i]);
  }
#pragma unroll
  for (int sh = 32; sh >= 1; sh >>= 1) vmax = fmaxf(vmax, __shfl_xor(vmax, sh));
  if (lane == 0) r1[wvi] = vmax;
  __syncthreads();
  float gmax = fmaxf(fmaxf(r1[0], r1[1]), fmaxf(r1[2], r1[3]));
  float e[4]; float es = 0.f;
#pragma unroll
  for (int i = 0; i < 4; ++i) { e[i] = __expf(tv[i] - gmax); es += e[i]; }
#pragma unroll
  for (int sh = 32; sh >= 1; sh >>= 1) es += __shfl_xor(es, sh);
  if (lane == 0) r2[wvi] = es;
  __syncthreads();
  float gsum = r2[0] + r2[1] + r2[2] + r2[3];
  float pv4[4]; float psum = 0.f;
#pragma unroll
  for (int i = 0; i < 4; ++i) { pv4[i] = e[i] / gsum * xmv[i]; psum += pv4[i]; }
#pragma unroll
  for (int sh = 32; sh >= 1; sh >>= 1) psum += __shfl_xor(psum, sh);
  if (lane == 0) r3[wvi] = psum;
  __syncthreads();
  float gps = r3[0] + r3[1] + r3[2] + r3[3];
  float inv = 1.f / (gps + 1e-13f);
#pragma unroll
  for (int i = 0; i < 4; ++i) ps_all[i * 256 + tid] = pv4[i] * inv;
  __syncthreads();
  const float* xb = x + ((size_t)b * XL_ + xc * 64) * D_;
  float acc0 = 0.f, acc1 = 0.f, acc2 = 0.f, acc3 = 0.f;
  int d = tid;
  const float* psl = ps_all + xc * 64;
  for (int xi = 0; xi < 64; ++xi) {
    float pv = psl[xi];
    const float* rp = xb + (size_t)xi * D_;
    acc0 += pv * __builtin_nontemporal_load(rp + d);
    acc1 += pv * __builtin_nontemporal_load(rp + d + 256);
    acc2 += pv * __builtin_nontemporal_load(rp + d + 512);
    acc3 += pv * __builtin_nontemporal_load(rp + d + 768);
  }
  float* pp = partial + (size_t)blockIdx.x * D_;
  pp[d] = acc0; pp[d + 256] = acc1; pp[d + 512] = acc2; pp[d + 768] = acc3;
}

// ---------- key2x reduce: k2x[b][d] = sum_xc partial ----------
__global__ __launch_bounds__(256) void k_key2x_red(const float* __restrict__ partial,
    float* __restrict__ k2x) {
  int idx = blockIdx.x * 256 + threadIdx.x;
  int b = idx >> 10;
  float s = 0.f;
#pragma unroll
  for (int xc = 0; xc < 16; ++xc)
    s += partial[((size_t)b * 16 + xc) * D_ + (idx & 1023)];
  k2x[idx] = s;
}

// ---------- streaming tail: out0 = x, out2 = x*x2key, out3 = x*key2x ----------
// Reads x (nt) and the x2key segment written by k_attn; pure streaming.
__global__ __launch_bounds__(256) void k_mega(const float* __restrict__ x,
    const float* __restrict__ k2x, float* __restrict__ out) {
  size_t t = (size_t)blockIdx.x * 256 + threadIdx.x;
  size_t base = t * 4;
  int b = (int)(base >> 20);
  int rem = (int)(base & ((1u << 20) - 1));
  int xr = rem >> 10;
  int d = rem & 1023;
  f32x4 xv = __builtin_nontemporal_load((const f32x4*)(x + base));
  f32x4 kv = *(const f32x4*)(k2x + (size_t)b * D_ + d);
  float* orow = out + ((size_t)b * XL_ + xr) * (size_t)(4 * D_);
  f32x4 x2 = __builtin_nontemporal_load((const f32x4*)(orow + D_ + d));
  __builtin_nontemporal_store(xv, (f32x4*)(orow + d));              // x
  f32x4 p2;
  p2[0] = xv[0] * x2[0]; p2[1] = xv[1] * x2[1];
  p2[2] = xv[2] * x2[2]; p2[3] = xv[3] * x2[3];
  __builtin_nontemporal_store(p2, (f32x4*)(orow + 2 * D_ + d));     // x * x2key
  f32x4 p3;
  p3[0] = xv[0] * kv[0]; p3[1] = xv[1] * kv[1];
  p3[2] = xv[2] * kv[2]; p3[3] = xv[3] * kv[3];
  __builtin_nontemporal_store(p3, (f32x4*)(orow + 3 * D_ + d));     // x * key2x
}

extern "C" void kernel_launch(void* const* d_in, const int* in_sizes, int n_in,
                              void* d_out, int out_size, void* d_ws, size_t ws_size,
                              hipStream_t stream) {
  (void)in_sizes; (void)n_in; (void)out_size; (void)ws_size;
  const float* x        = (const float*)d_in[0];
  const float* x_mask   = (const float*)d_in[1];
  const float* key      = (const float*)d_in[2];
  const float* key_mask = (const float*)d_in[3];
  const float* w_input  = (const float*)d_in[4];
  const float* w_key    = (const float*)d_in[5];
  const float* dot_w    = (const float*)d_in[6];
  float* out = (float*)d_out;
  char* ws = (char*)d_ws;

  unsigned short* KQ2 = (unsigned short*)ws;                        // 16 MB
  unsigned short* KV2 = (unsigned short*)(ws + (16u << 20));        // 16 MB
  float* xlog = (float*)(ws + (32u << 20));                         // 64 KB (unused)
  float* klog = xlog + B_ * XL_;                                    // 32 KB
  float* maxs = klog + B_ * KL_;                                    // 64 KB
  float* pbuf = maxs + B_ * XL_;                                    // 64 KB (unused)
  float* k2x  = pbuf + B_ * XL_;                                    // 64 KB
  float* partial = (float*)ws;   // 1 MB, aliases KQ2 (dead after k_attn)

  hipMemsetAsync(klog, 0, B_ * KL_ * sizeof(float), stream);
  k_build<<<dim3(B_ * 16), dim3(256), 0, stream>>>(key, w_key, KQ2, KV2, klog);
  k_attn<<<dim3(512), dim3(512), 0, stream>>>(x, x_mask, key_mask, dot_w, w_input,
                                              KQ2, KV2, klog, maxs, out);
  k_key2x_part<<<dim3(B_ * 16), dim3(256), 0, stream>>>(x, maxs, x_mask, partial);
  k_key2x_red<<<dim3(B_ * D_ / 256), dim3(256), 0, stream>>>(partial, k2x);
  k_mega<<<dim3(B_ * XL_ * D_ / 1024), dim3(256), 0, stream>>>(x, k2x, out);
}

// Round 10
// 163.526 us; speedup vs baseline: 1.1302x; 1.0343x over previous
//
#include <hip/hip_runtime.h>
#include <hip/hip_fp16.h>

#define B_ 16
#define XL_ 1024
#define KL_ 512
#define D_ 1024
#define NEGC (-10000000.0f)

typedef _Float16 f16x8 __attribute__((ext_vector_type(8)));
typedef float f32x4 __attribute__((ext_vector_type(4)));
typedef unsigned short u16x8 __attribute__((ext_vector_type(8)));
typedef unsigned short u16x4 __attribute__((ext_vector_type(4)));

__device__ __forceinline__ unsigned short f2h(float f) {
  __half h = __float2half(f);
  return __half_as_ushort(h);
}

// ---------- build fragment-order K arrays + klog partial planes ----------
// klogP[dh][b*KL+k]: each d-half block writes its own plane (no atomics).
__global__ __launch_bounds__(256) void k_build(const float* __restrict__ key,
    const float* __restrict__ w_key, unsigned short* __restrict__ KQ2,
    unsigned short* __restrict__ KV2, float* __restrict__ klogP) {
  __shared__ unsigned short tile[64][72];
  int bid = blockIdx.x;
  int b = bid >> 4;
  int ks = (bid >> 1) & 7;
  int dh = bid & 1;
  int tid = threadIdx.x;
  int kr = tid >> 2;          // local k-row 0..63
  int cq = tid & 3;           // col quarter
  const float* krow = key + ((size_t)(b * KL_ + ks * 64 + kr)) * D_;
  float klacc = 0.f;
  int dl = tid & 63, g = tid >> 6;

  for (int dt = dh * 8; dt < dh * 8 + 8; ++dt) {
#pragma unroll
    for (int j = 0; j < 4; ++j) {
      int c = dt * 64 + cq * 16 + j * 4;
      f32x4 v = __builtin_nontemporal_load((const f32x4*)(krow + c));
      f32x4 w = *(const f32x4*)(w_key + c);
      klacc += v[0] * w[0] + v[1] * w[1] + v[2] * w[2] + v[3] * w[3];
      u16x4 hv;
      hv[0] = f2h(v[0]); hv[1] = f2h(v[1]); hv[2] = f2h(v[2]); hv[3] = f2h(v[3]);
      *(u16x4*)(&tile[kr][cq * 16 + j * 4]) = hv;
    }
    __syncthreads();
#pragma unroll
    for (int dkc_l = 0; dkc_l < 2; ++dkc_l) {
      u16x8 hv = *(const u16x8*)(&tile[kr][dkc_l * 32 + cq * 8]);
      size_t dst = (((size_t)(b * 8 + ks) * 32 + (dt * 2 + dkc_l)) << 11)
                   + (size_t)(((kr >> 4) & 3) * 512 + (cq * 16 + (kr & 15)) * 8);
      *(u16x8*)(KQ2 + dst) = hv;
    }
    {
      int dglob = dt * 64 + dl;
      int wv_ = dglob >> 7, np = (dglob >> 4) & 7, l15v = dglob & 15;
#pragma unroll
      for (int kkc_l = 0; kkc_l < 2; ++kkc_l) {
        u16x8 hv;
#pragma unroll
        for (int h = 0; h < 8; ++h) hv[h] = tile[kkc_l * 32 + g * 8 + h][dl];
        size_t dst = (((size_t)(b * 8 + wv_) * 16 + (ks * 2 + kkc_l)) << 12)
                     + (size_t)(np * 512 + (g * 16 + l15v) * 8);
        *(u16x8*)(KV2 + dst) = hv;
      }
    }
    __syncthreads();
  }
  klacc += __shfl_xor(klacc, 1);
  klacc += __shfl_xor(klacc, 2);
  if (cq == 0) klogP[(size_t)dh * (B_ * KL_) + b * KL_ + ks * 64 + kr] = klacc;
}

// ---------- main attention kernel ----------
// R9 structure + issue-early prefetch: 512 thr (8 waves), 32 x-rows x KL=512,
// 512 blocks (2/CU). Dense fragment-order K loads with depth-1 rotation;
// first-iteration loads hoisted across barriers (T14).
__global__ __launch_bounds__(512, 4) void k_attn(
    const float* __restrict__ x, const float* __restrict__ x_mask,
    const float* __restrict__ key_mask, const float* __restrict__ dot_w,
    const float* __restrict__ w_input,
    const unsigned short* __restrict__ KQ2, const unsigned short* __restrict__ KV2,
    const float* __restrict__ klogP,
    float* __restrict__ maxs, float* __restrict__ out) {
  __shared__ unsigned short Qall[32 * 1024];        // 64KB
  __shared__ float xlg[32];                         // fused x_logits
  unsigned short* Pt = Qall;                        // alias: 32KB P tile
  float* redA = (float*)(Qall + 16384);             // byte 32768+
  float* redB = redA + 256;
  float* redC = redB + 256;

  const int tid = threadIdx.x;
  const int wv = tid >> 6;
  const int lane = tid & 63;
  const int l15 = lane & 15, l4 = lane >> 4;
  const int r7 = l15 & 7;

  int bid = blockIdx.x;
  int b = (bid & 7) * 2 + (bid >> 8);
  int x0 = ((bid >> 3) & 31) * 32;

  const float* xB = x + ((size_t)b * XL_ + x0) * D_;
  const unsigned short* KQ2w = KQ2 + (((size_t)(b * 8 + wv) * 32) << 11) + lane * 8;

  // prefetch QK^T first-iteration K frags (no LDS dependency) [T14]
  f16x8 nq0 = *(const f16x8*)(KQ2w);
  f16x8 nq1 = *(const f16x8*)(KQ2w + 512);
  f16x8 nq2 = *(const f16x8*)(KQ2w + 1024);
  f16x8 nq3 = *(const f16x8*)(KQ2w + 1536);

  // ---- stage Q = fp16(x * dot_w); fused x_logits ----
  {
    int row = tid >> 4;
    int cg = tid & 15;
    const float* sp = xB + (size_t)row * D_;
    char* qrow = (char*)Qall + row * 2048;
    int rsw = row & 7;
    float xl = 0.f;
#pragma unroll
    for (int j = 0; j < 16; ++j) {
      int c4 = cg + j * 16;
      f32x4 v = *(const f32x4*)(sp + c4 * 4);
      f32x4 w = *(const f32x4*)(dot_w + c4 * 4);
      f32x4 wi = *(const f32x4*)(w_input + c4 * 4);
      xl += v[0] * wi[0] + v[1] * wi[1] + v[2] * wi[2] + v[3] * wi[3];
      u16x4 hv;
      hv[0] = f2h(v[0] * w[0]); hv[1] = f2h(v[1] * w[1]);
      hv[2] = f2h(v[2] * w[2]); hv[3] = f2h(v[3] * w[3]);
      *(u16x4*)(qrow + (((c4 >> 1) ^ rsw) << 4) + ((c4 & 1) << 3)) = hv;
    }
    xl += __shfl_xor(xl, 1);
    xl += __shfl_xor(xl, 2);
    xl += __shfl_xor(xl, 4);
    xl += __shfl_xor(xl, 8);
    if (cg == 0) xlg[row] = xl;
  }
  __syncthreads();

  // ---- QK^T: acc[m][n] = mfma(Kfrag_n, Qfrag_m), rotated dense loads ----
  f32x4 acc[2][4];
#pragma unroll
  for (int m = 0; m < 2; ++m)
#pragma unroll
    for (int n = 0; n < 4; ++n) { f32x4 z = {0.f, 0.f, 0.f, 0.f}; acc[m][n] = z; }

  const char* qa0 = (char*)Qall + l15 * 2048;
  const char* qa1 = (char*)Qall + (16 + l15) * 2048;

#pragma unroll 4
  for (int dk = 0; dk < D_; dk += 32) {
    f16x8 b0 = nq0, b1 = nq1, b2 = nq2, b3 = nq3;
    if (dk + 32 < D_) {
      const unsigned short* cp = KQ2w + (((dk + 32) >> 5) << 11);
      nq0 = *(const f16x8*)(cp);
      nq1 = *(const f16x8*)(cp + 512);
      nq2 = *(const f16x8*)(cp + 1024);
      nq3 = *(const f16x8*)(cp + 1536);
    }
    int c = (((dk >> 3) + l4) ^ r7) << 4;
    f16x8 a0 = *(const f16x8*)(qa0 + c);
    f16x8 a1 = *(const f16x8*)(qa1 + c);
    __builtin_amdgcn_s_setprio(1);
    acc[0][0] = __builtin_amdgcn_mfma_f32_16x16x32_f16(b0, a0, acc[0][0], 0, 0, 0);
    acc[1][0] = __builtin_amdgcn_mfma_f32_16x16x32_f16(b0, a1, acc[1][0], 0, 0, 0);
    acc[0][1] = __builtin_amdgcn_mfma_f32_16x16x32_f16(b1, a0, acc[0][1], 0, 0, 0);
    acc[1][1] = __builtin_amdgcn_mfma_f32_16x16x32_f16(b1, a1, acc[1][1], 0, 0, 0);
    acc[0][2] = __builtin_amdgcn_mfma_f32_16x16x32_f16(b2, a0, acc[0][2], 0, 0, 0);
    acc[1][2] = __builtin_amdgcn_mfma_f32_16x16x32_f16(b2, a1, acc[1][2], 0, 0, 0);
    acc[0][3] = __builtin_amdgcn_mfma_f32_16x16x32_f16(b3, a0, acc[0][3], 0, 0, 0);
    acc[1][3] = __builtin_amdgcn_mfma_f32_16x16x32_f16(b3, a1, acc[1][3], 0, 0, 0);
    __builtin_amdgcn_s_setprio(0);
  }
  __syncthreads();   // Q region dead beyond this point

  // prefetch PV sc=0 first-iteration KV2 frags; latency hides under softmax [T14]
  const unsigned short* KV2w = KV2 + (((size_t)(b * 8 + wv) * 16) << 12) + lane * 8;
  f16x8 pv0 = *(const f16x8*)(KV2w);
  f16x8 pv1 = *(const f16x8*)(KV2w + 512);
  f16x8 pv2 = *(const f16x8*)(KV2w + 1024);
  f16x8 pv3 = *(const f16x8*)(KV2w + 1536);

  // ---- softmax over KL ----
  float xlv[2], xmv[2];
#pragma unroll
  for (int m = 0; m < 2; ++m) {
    int row = m * 16 + l15;
    xlv[m] = xlg[row];
    xmv[m] = x_mask[(size_t)b * XL_ + x0 + row];
  }
  f32x4 klv[4], kmv[4];
#pragma unroll
  for (int n = 0; n < 4; ++n) {
    int kb = wv * 64 + n * 16 + l4 * 4;
    f32x4 ka = *(const f32x4*)(klogP + (size_t)b * KL_ + kb);
    f32x4 kb2 = *(const f32x4*)(klogP + (size_t)(B_ * KL_) + (size_t)b * KL_ + kb);
    klv[n] = ka + kb2;
    kmv[n] = *(const f32x4*)(key_mask + (size_t)b * KL_ + kb);
  }
  float mxsm[2] = {-3.0e38f, -3.0e38f}, mxs2[2] = {-3.0e38f, -3.0e38f};
#pragma unroll
  for (int m = 0; m < 2; ++m)
#pragma unroll
    for (int n = 0; n < 4; ++n)
#pragma unroll
      for (int q = 0; q < 4; ++q) {
        float s = acc[m][n][q] + xlv[m] + klv[n][q];
        float sm = s + (1.f - xmv[m] * kmv[n][q]) * NEGC;
        float s2 = s * kmv[n][q] + (1.f - kmv[n][q]) * NEGC;
        mxsm[m] = fmaxf(mxsm[m], sm);
        mxs2[m] = fmaxf(mxs2[m], s2);
      }
#pragma unroll
  for (int m = 0; m < 2; ++m) {
    mxsm[m] = fmaxf(mxsm[m], __shfl_xor(mxsm[m], 16));
    mxsm[m] = fmaxf(mxsm[m], __shfl_xor(mxsm[m], 32));
    mxs2[m] = fmaxf(mxs2[m], __shfl_xor(mxs2[m], 16));
    mxs2[m] = fmaxf(mxs2[m], __shfl_xor(mxs2[m], 32));
  }
  if (l4 == 0) {
#pragma unroll
    for (int m = 0; m < 2; ++m) {
      redA[wv * 32 + m * 16 + l15] = mxsm[m];
      redB[wv * 32 + m * 16 + l15] = mxs2[m];
    }
  }
  __syncthreads();
  float gmx[2];
#pragma unroll
  for (int m = 0; m < 2; ++m) {
    int row = m * 16 + l15;
    float v = redA[row];
#pragma unroll
    for (int w = 1; w < 8; ++w) v = fmaxf(v, redA[w * 32 + row]);
    gmx[m] = v;
  }
  if (tid < 32) {
    float v = redB[tid];
#pragma unroll
    for (int w = 1; w < 8; ++w) v = fmaxf(v, redB[w * 32 + tid]);
    maxs[(size_t)b * XL_ + x0 + tid] = v;
  }
  // exp pass: P^ written as [x-row][k] fp16, 8B granules, XOR-swizzled
  float rs[2] = {0.f, 0.f};
#pragma unroll
  for (int m = 0; m < 2; ++m) {
    int row = m * 16 + l15;
    char* prow = (char*)Pt + row * 1024;
    int rsw = row & 7;
#pragma unroll
    for (int n = 0; n < 4; ++n) {
      int k = wv * 64 + n * 16 + l4 * 4;
      u16x4 pk;
#pragma unroll
      for (int q = 0; q < 4; ++q) {
        float s = acc[m][n][q] + xlv[m] + klv[n][q];
        float sm = s + (1.f - xmv[m] * kmv[n][q]) * NEGC;
        float e = __expf(sm - gmx[m]);
        rs[m] += e;
        pk[q] = f2h(e);
      }
      *(u16x4*)(prow + ((((k >> 3) ^ rsw) << 4) + ((k & 4) << 1))) = pk;
    }
  }
#pragma unroll
  for (int m = 0; m < 2; ++m) {
    rs[m] += __shfl_xor(rs[m], 16);
    rs[m] += __shfl_xor(rs[m], 32);
  }
  if (l4 == 0) {
#pragma unroll
    for (int m = 0; m < 2; ++m) redC[wv * 32 + m * 16 + l15] = rs[m];
  }
  __syncthreads();

  // ---- PV: acc2[m][n] = mfma(KhTfrag_n, Pfrag_m), rotated dense loads ----
  float dn[2];
#pragma unroll
  for (int m = 0; m < 2; ++m) {
    int row = m * 16 + l15;
    float sum = redC[row];
#pragma unroll
    for (int w = 1; w < 8; ++w) sum += redC[w * 32 + row];
    dn[m] = 1.f / sum;
  }
  size_t obase0 = ((size_t)b * XL_ + x0) * (size_t)(4 * D_);
  const char* pa0 = (char*)Pt + l15 * 1024;
  const char* pa1 = (char*)Pt + (16 + l15) * 1024;
#pragma unroll
  for (int sc = 0; sc < 2; ++sc) {
    int c0 = wv * 128 + sc * 64;
    f32x4 acc2[2][4];
#pragma unroll
    for (int m = 0; m < 2; ++m)
#pragma unroll
      for (int n = 0; n < 4; ++n) { f32x4 z = {0.f, 0.f, 0.f, 0.f}; acc2[m][n] = z; }
    const unsigned short* KV2s = KV2w + sc * 4 * 512;
    f16x8 nb0, nb1, nb2, nb3;
    if (sc == 0) { nb0 = pv0; nb1 = pv1; nb2 = pv2; nb3 = pv3; }
    else {
      nb0 = *(const f16x8*)(KV2s);
      nb1 = *(const f16x8*)(KV2s + 512);
      nb2 = *(const f16x8*)(KV2s + 1024);
      nb3 = *(const f16x8*)(KV2s + 1536);
    }
#pragma unroll 4
    for (int kk = 0; kk < KL_; kk += 32) {
      f16x8 b0 = nb0, b1 = nb1, b2 = nb2, b3 = nb3;
      if (kk + 32 < KL_) {
        const unsigned short* cp = KV2s + (((kk + 32) >> 5) << 12);
        nb0 = *(const f16x8*)(cp);
        nb1 = *(const f16x8*)(cp + 512);
        nb2 = *(const f16x8*)(cp + 1024);
        nb3 = *(const f16x8*)(cp + 1536);
      }
      int c = ((((kk >> 3) + l4) ^ r7) << 4);
      f16x8 a0 = *(const f16x8*)(pa0 + c);
      f16x8 a1 = *(const f16x8*)(pa1 + c);
      __builtin_amdgcn_s_setprio(1);
      acc2[0][0] = __builtin_amdgcn_mfma_f32_16x16x32_f16(b0, a0, acc2[0][0], 0, 0, 0);
      acc2[1][0] = __builtin_amdgcn_mfma_f32_16x16x32_f16(b0, a1, acc2[1][0], 0, 0, 0);
      acc2[0][1] = __builtin_amdgcn_mfma_f32_16x16x32_f16(b1, a0, acc2[0][1], 0, 0, 0);
      acc2[1][1] = __builtin_amdgcn_mfma_f32_16x16x32_f16(b1, a1, acc2[1][1], 0, 0, 0);
      acc2[0][2] = __builtin_amdgcn_mfma_f32_16x16x32_f16(b2, a0, acc2[0][2], 0, 0, 0);
      acc2[1][2] = __builtin_amdgcn_mfma_f32_16x16x32_f16(b2, a1, acc2[1][2], 0, 0, 0);
      acc2[0][3] = __builtin_amdgcn_mfma_f32_16x16x32_f16(b3, a0, acc2[0][3], 0, 0, 0);
      acc2[1][3] = __builtin_amdgcn_mfma_f32_16x16x32_f16(b3, a1, acc2[1][3], 0, 0, 0);
      __builtin_amdgcn_s_setprio(0);
    }
#pragma unroll
    for (int m = 0; m < 2; ++m) {
      int row = m * 16 + l15;
      size_t ob = obase0 + (size_t)row * (4 * D_);
#pragma unroll
      for (int n = 0; n < 4; ++n) {
        int col = c0 + n * 16 + l4 * 4;
        f32x4 v = acc2[m][n];
        v[0] *= dn[m]; v[1] *= dn[m]; v[2] *= dn[m]; v[3] *= dn[m];
        __builtin_nontemporal_store(v, (f32x4*)(out + ob + D_ + col));  // x2key only
      }
    }
  }
}

// ---------- key2x partials with fused p-softmax: block (b, xc) ----------
__global__ __launch_bounds__(256) void k_key2x_part(const float* __restrict__ x,
    const float* __restrict__ maxs, const float* __restrict__ x_mask,
    float* __restrict__ partial) {
  int b = blockIdx.x >> 4;
  int xc = blockIdx.x & 15;
  int tid = threadIdx.x;
  int wvi = tid >> 6, lane = tid & 63;
  __shared__ float r1[4], r2[4], r3[4];
  __shared__ float ps_all[XL_];
  const float* ms = maxs + (size_t)b * XL_;
  const float* xm = x_mask + (size_t)b * XL_;
  float tv[4], xmv[4];
  float vmax = -3.0e38f;
#pragma unroll
  for (int i = 0; i < 4; ++i) {
    int xi = i * 256 + tid;
    xmv[i] = xm[xi];
    tv[i] = ms[xi] * xmv[i];
    vmax = fmaxf(vmax, tv[i]);
  }
#pragma unroll
  for (int sh = 32; sh >= 1; sh >>= 1) vmax = fmaxf(vmax, __shfl_xor(vmax, sh));
  if (lane == 0) r1[wvi] = vmax;
  __syncthreads();
  float gmax = fmaxf(fmaxf(r1[0], r1[1]), fmaxf(r1[2], r1[3]));
  float e[4]; float es = 0.f;
#pragma unroll
  for (int i = 0; i < 4; ++i) { e[i] = __expf(tv[i] - gmax); es += e[i]; }
#pragma unroll
  for (int sh = 32; sh >= 1; sh >>= 1) es += __shfl_xor(es, sh);
  if (lane == 0) r2[wvi] = es;
  __syncthreads();
  float gsum = r2[0] + r2[1] + r2[2] + r2[3];
  float pv4[4]; float psum = 0.f;
#pragma unroll
  for (int i = 0; i < 4; ++i) { pv4[i] = e[i] / gsum * xmv[i]; psum += pv4[i]; }
#pragma unroll
  for (int sh = 32; sh >= 1; sh >>= 1) psum += __shfl_xor(psum, sh);
  if (lane == 0) r3[wvi] = psum;
  __syncthreads();
  float gps = r3[0] + r3[1] + r3[2] + r3[3];
  float inv = 1.f / (gps + 1e-13f);
#pragma unroll
  for (int i = 0; i < 4; ++i) ps_all[i * 256 + tid] = pv4[i] * inv;
  __syncthreads();
  const float* xb = x + ((size_t)b * XL_ + xc * 64) * D_;
  float acc0 = 0.f, acc1 = 0.f, acc2 = 0.f, acc3 = 0.f;
  int d = tid;
  const float* psl = ps_all + xc * 64;
  for (int xi = 0; xi < 64; ++xi) {
    float pv = psl[xi];
    const float* rp = xb + (size_t)xi * D_;
    acc0 += pv * __builtin_nontemporal_load(rp + d);
    acc1 += pv * __builtin_nontemporal_load(rp + d + 256);
    acc2 += pv * __builtin_nontemporal_load(rp + d + 512);
    acc3 += pv * __builtin_nontemporal_load(rp + d + 768);
  }
  float* pp = partial + (size_t)blockIdx.x * D_;
  pp[d] = acc0; pp[d + 256] = acc1; pp[d + 512] = acc2; pp[d + 768] = acc3;
}

// ---------- key2x reduce: k2x[b][d] = sum_xc partial ----------
__global__ __launch_bounds__(256) void k_key2x_red(const float* __restrict__ partial,
    float* __restrict__ k2x) {
  int idx = blockIdx.x * 256 + threadIdx.x;
  int b = idx >> 10;
  float s = 0.f;
#pragma unroll
  for (int xc = 0; xc < 16; ++xc)
    s += partial[((size_t)b * 16 + xc) * D_ + (idx & 1023)];
  k2x[idx] = s;
}

// ---------- streaming tail: out0 = x, out2 = x*x2key, out3 = x*key2x ----------
__global__ __launch_bounds__(256) void k_mega(const float* __restrict__ x,
    const float* __restrict__ k2x, float* __restrict__ out) {
  size_t t = (size_t)blockIdx.x * 256 + threadIdx.x;
  size_t base = t * 4;
  int b = (int)(base >> 20);
  int rem = (int)(base & ((1u << 20) - 1));
  int xr = rem >> 10;
  int d = rem & 1023;
  f32x4 xv = __builtin_nontemporal_load((const f32x4*)(x + base));
  f32x4 kv = *(const f32x4*)(k2x + (size_t)b * D_ + d);
  float* orow = out + ((size_t)b * XL_ + xr) * (size_t)(4 * D_);
  f32x4 x2 = __builtin_nontemporal_load((const f32x4*)(orow + D_ + d));
  __builtin_nontemporal_store(xv, (f32x4*)(orow + d));              // x
  f32x4 p2;
  p2[0] = xv[0] * x2[0]; p2[1] = xv[1] * x2[1];
  p2[2] = xv[2] * x2[2]; p2[3] = xv[3] * x2[3];
  __builtin_nontemporal_store(p2, (f32x4*)(orow + 2 * D_ + d));     // x * x2key
  f32x4 p3;
  p3[0] = xv[0] * kv[0]; p3[1] = xv[1] * kv[1];
  p3[2] = xv[2] * kv[2]; p3[3] = xv[3] * kv[3];
  __builtin_nontemporal_store(p3, (f32x4*)(orow + 3 * D_ + d));     // x * key2x
}

extern "C" void kernel_launch(void* const* d_in, const int* in_sizes, int n_in,
                              void* d_out, int out_size, void* d_ws, size_t ws_size,
                              hipStream_t stream) {
  (void)in_sizes; (void)n_in; (void)out_size; (void)ws_size;
  const float* x        = (const float*)d_in[0];
  const float* x_mask   = (const float*)d_in[1];
  const float* key      = (const float*)d_in[2];
  const float* key_mask = (const float*)d_in[3];
  const float* w_input  = (const float*)d_in[4];
  const float* w_key    = (const float*)d_in[5];
  const float* dot_w    = (const float*)d_in[6];
  float* out = (float*)d_out;
  char* ws = (char*)d_ws;

  unsigned short* KQ2 = (unsigned short*)ws;                        // 16 MB
  unsigned short* KV2 = (unsigned short*)(ws + (16u << 20));        // 16 MB
  float* klogP = (float*)(ws + (32u << 20));                        // 2x32 KB planes
  float* maxs = klogP + 2 * B_ * KL_;                               // 64 KB
  float* k2x  = maxs + B_ * XL_;                                    // 64 KB
  float* partial = (float*)ws;   // 1 MB, aliases KQ2 (dead after k_attn)

  k_build<<<dim3(B_ * 16), dim3(256), 0, stream>>>(key, w_key, KQ2, KV2, klogP);
  k_attn<<<dim3(512), dim3(512), 0, stream>>>(x, x_mask, key_mask, dot_w, w_input,
                                              KQ2, KV2, klogP, maxs, out);
  k_key2x_part<<<dim3(B_ * 16), dim3(256), 0, stream>>>(x, maxs, x_mask, partial);
  k_key2x_red<<<dim3(B_ * D_ / 256), dim3(256), 0, stream>>>(partial, k2x);
  k_mega<<<dim3(B_ * XL_ * D_ / 1024), dim3(256), 0, stream>>>(x, k2x, out);
}

// Round 11
// 162.960 us; speedup vs baseline: 1.1341x; 1.0035x over previous
//
#include <hip/hip_runtime.h>
#include <hip/hip_fp16.h>

#define B_ 16
#define XL_ 1024
#define KL_ 512
#define D_ 1024
#define NEGC (-10000000.0f)

typedef _Float16 f16x8 __attribute__((ext_vector_type(8)));
typedef float f32x4 __attribute__((ext_vector_type(4)));
typedef unsigned short u16x8 __attribute__((ext_vector_type(8)));
typedef unsigned short u16x4 __attribute__((ext_vector_type(4)));

__device__ __forceinline__ unsigned short f2h(float f) {
  __half h = __float2half(f);
  return __half_as_ushort(h);
}

// ---------- build fragment-order K arrays + klog partial planes ----------
// Block = (b, ks 64-row strip, dq quarter of 4 d-tiles); 512 blocks (2/CU).
// klogP[dq][b*KL+k]: each d-quarter block writes its own plane (no atomics).
__global__ __launch_bounds__(256) void k_build(const float* __restrict__ key,
    const float* __restrict__ w_key, unsigned short* __restrict__ KQ2,
    unsigned short* __restrict__ KV2, float* __restrict__ klogP) {
  __shared__ unsigned short tile[64][72];
  int bid = blockIdx.x;
  int b = bid >> 5;
  int ks = (bid >> 2) & 7;
  int dq = bid & 3;
  int tid = threadIdx.x;
  int kr = tid >> 2;          // local k-row 0..63
  int cq = tid & 3;           // col quarter
  const float* krow = key + ((size_t)(b * KL_ + ks * 64 + kr)) * D_;
  float klacc = 0.f;
  int dl = tid & 63, g = tid >> 6;

  for (int dt = dq * 4; dt < dq * 4 + 4; ++dt) {
#pragma unroll
    for (int j = 0; j < 4; ++j) {
      int c = dt * 64 + cq * 16 + j * 4;
      f32x4 v = __builtin_nontemporal_load((const f32x4*)(krow + c));
      f32x4 w = *(const f32x4*)(w_key + c);
      klacc += v[0] * w[0] + v[1] * w[1] + v[2] * w[2] + v[3] * w[3];
      u16x4 hv;
      hv[0] = f2h(v[0]); hv[1] = f2h(v[1]); hv[2] = f2h(v[2]); hv[3] = f2h(v[3]);
      *(u16x4*)(&tile[kr][cq * 16 + j * 4]) = hv;
    }
    __syncthreads();
#pragma unroll
    for (int dkc_l = 0; dkc_l < 2; ++dkc_l) {
      u16x8 hv = *(const u16x8*)(&tile[kr][dkc_l * 32 + cq * 8]);
      size_t dst = (((size_t)(b * 8 + ks) * 32 + (dt * 2 + dkc_l)) << 11)
                   + (size_t)(((kr >> 4) & 3) * 512 + (cq * 16 + (kr & 15)) * 8);
      *(u16x8*)(KQ2 + dst) = hv;
    }
    {
      int dglob = dt * 64 + dl;
      int wv_ = dglob >> 7, np = (dglob >> 4) & 7, l15v = dglob & 15;
#pragma unroll
      for (int kkc_l = 0; kkc_l < 2; ++kkc_l) {
        u16x8 hv;
#pragma unroll
        for (int h = 0; h < 8; ++h) hv[h] = tile[kkc_l * 32 + g * 8 + h][dl];
        size_t dst = (((size_t)(b * 8 + wv_) * 16 + (ks * 2 + kkc_l)) << 12)
                     + (size_t)(np * 512 + (g * 16 + l15v) * 8);
        *(u16x8*)(KV2 + dst) = hv;
      }
    }
    __syncthreads();
  }
  klacc += __shfl_xor(klacc, 1);
  klacc += __shfl_xor(klacc, 2);
  if (cq == 0) klogP[(size_t)dq * (B_ * KL_) + b * KL_ + ks * 64 + kr] = klacc;
}

// ---------- main attention kernel ----------
// R10 structure + depth-2 load rotation: 512 thr (8 waves), 32 x-rows x
// KL=512, 512 blocks (2/CU). Dense fragment-order K loads, 2 iterations
// in flight; first-iteration loads hoisted across barriers (T14).
__global__ __launch_bounds__(512, 4) void k_attn(
    const float* __restrict__ x, const float* __restrict__ x_mask,
    const float* __restrict__ key_mask, const float* __restrict__ dot_w,
    const float* __restrict__ w_input,
    const unsigned short* __restrict__ KQ2, const unsigned short* __restrict__ KV2,
    const float* __restrict__ klogP,
    float* __restrict__ maxs, float* __restrict__ out) {
  __shared__ unsigned short Qall[32 * 1024];        // 64KB
  __shared__ float xlg[32];                         // fused x_logits
  unsigned short* Pt = Qall;                        // alias: 32KB P tile
  float* redA = (float*)(Qall + 16384);             // byte 32768+
  float* redB = redA + 256;
  float* redC = redB + 256;

  const int tid = threadIdx.x;
  const int wv = tid >> 6;
  const int lane = tid & 63;
  const int l15 = lane & 15, l4 = lane >> 4;
  const int r7 = l15 & 7;

  int bid = blockIdx.x;
  int b = (bid & 7) * 2 + (bid >> 8);
  int x0 = ((bid >> 3) & 31) * 32;

  const float* xB = x + ((size_t)b * XL_ + x0) * D_;
  const unsigned short* KQ2w = KQ2 + (((size_t)(b * 8 + wv) * 32) << 11) + lane * 8;

  // prefetch QK^T chunk0+chunk1 K frags (no LDS dependency) [T14]
  f16x8 p00 = *(const f16x8*)(KQ2w);
  f16x8 p01 = *(const f16x8*)(KQ2w + 512);
  f16x8 p02 = *(const f16x8*)(KQ2w + 1024);
  f16x8 p03 = *(const f16x8*)(KQ2w + 1536);
  f16x8 p10 = *(const f16x8*)(KQ2w + 2048);
  f16x8 p11 = *(const f16x8*)(KQ2w + 2048 + 512);
  f16x8 p12 = *(const f16x8*)(KQ2w + 2048 + 1024);
  f16x8 p13 = *(const f16x8*)(KQ2w + 2048 + 1536);

  // ---- stage Q = fp16(x * dot_w); fused x_logits ----
  {
    int row = tid >> 4;
    int cg = tid & 15;
    const float* sp = xB + (size_t)row * D_;
    char* qrow = (char*)Qall + row * 2048;
    int rsw = row & 7;
    float xl = 0.f;
#pragma unroll
    for (int j = 0; j < 16; ++j) {
      int c4 = cg + j * 16;
      f32x4 v = *(const f32x4*)(sp + c4 * 4);
      f32x4 w = *(const f32x4*)(dot_w + c4 * 4);
      f32x4 wi = *(const f32x4*)(w_input + c4 * 4);
      xl += v[0] * wi[0] + v[1] * wi[1] + v[2] * wi[2] + v[3] * wi[3];
      u16x4 hv;
      hv[0] = f2h(v[0] * w[0]); hv[1] = f2h(v[1] * w[1]);
      hv[2] = f2h(v[2] * w[2]); hv[3] = f2h(v[3] * w[3]);
      *(u16x4*)(qrow + (((c4 >> 1) ^ rsw) << 4) + ((c4 & 1) << 3)) = hv;
    }
    xl += __shfl_xor(xl, 1);
    xl += __shfl_xor(xl, 2);
    xl += __shfl_xor(xl, 4);
    xl += __shfl_xor(xl, 8);
    if (cg == 0) xlg[row] = xl;
  }
  __syncthreads();

  // ---- QK^T: acc[m][n] = mfma(Kfrag_n, Qfrag_m), depth-2 rotation ----
  f32x4 acc[2][4];
#pragma unroll
  for (int m = 0; m < 2; ++m)
#pragma unroll
    for (int n = 0; n < 4; ++n) { f32x4 z = {0.f, 0.f, 0.f, 0.f}; acc[m][n] = z; }

  const char* qa0 = (char*)Qall + l15 * 2048;
  const char* qa1 = (char*)Qall + (16 + l15) * 2048;

#pragma unroll 2
  for (int dk = 0; dk < D_; dk += 64) {
    // ---- sub-iter A: chunk dk/32 (regs p0x); reload p0x <- chunk +2 ----
    {
      f16x8 b0 = p00, b1 = p01, b2 = p02, b3 = p03;
      if (dk + 64 < D_) {
        const unsigned short* cp = KQ2w + (((dk + 64) >> 5) << 11);
        p00 = *(const f16x8*)(cp);
        p01 = *(const f16x8*)(cp + 512);
        p02 = *(const f16x8*)(cp + 1024);
        p03 = *(const f16x8*)(cp + 1536);
      }
      int c = (((dk >> 3) + l4) ^ r7) << 4;
      f16x8 a0 = *(const f16x8*)(qa0 + c);
      f16x8 a1 = *(const f16x8*)(qa1 + c);
      __builtin_amdgcn_s_setprio(1);
      acc[0][0] = __builtin_amdgcn_mfma_f32_16x16x32_f16(b0, a0, acc[0][0], 0, 0, 0);
      acc[1][0] = __builtin_amdgcn_mfma_f32_16x16x32_f16(b0, a1, acc[1][0], 0, 0, 0);
      acc[0][1] = __builtin_amdgcn_mfma_f32_16x16x32_f16(b1, a0, acc[0][1], 0, 0, 0);
      acc[1][1] = __builtin_amdgcn_mfma_f32_16x16x32_f16(b1, a1, acc[1][1], 0, 0, 0);
      acc[0][2] = __builtin_amdgcn_mfma_f32_16x16x32_f16(b2, a0, acc[0][2], 0, 0, 0);
      acc[1][2] = __builtin_amdgcn_mfma_f32_16x16x32_f16(b2, a1, acc[1][2], 0, 0, 0);
      acc[0][3] = __builtin_amdgcn_mfma_f32_16x16x32_f16(b3, a0, acc[0][3], 0, 0, 0);
      acc[1][3] = __builtin_amdgcn_mfma_f32_16x16x32_f16(b3, a1, acc[1][3], 0, 0, 0);
      __builtin_amdgcn_s_setprio(0);
    }
    // ---- sub-iter B: chunk dk/32+1 (regs p1x); reload p1x <- chunk +3 ----
    {
      int dk2 = dk + 32;
      f16x8 b0 = p10, b1 = p11, b2 = p12, b3 = p13;
      if (dk2 + 64 < D_) {
        const unsigned short* cp = KQ2w + (((dk2 + 64) >> 5) << 11);
        p10 = *(const f16x8*)(cp);
        p11 = *(const f16x8*)(cp + 512);
        p12 = *(const f16x8*)(cp + 1024);
        p13 = *(const f16x8*)(cp + 1536);
      }
      int c = (((dk2 >> 3) + l4) ^ r7) << 4;
      f16x8 a0 = *(const f16x8*)(qa0 + c);
      f16x8 a1 = *(const f16x8*)(qa1 + c);
      __builtin_amdgcn_s_setprio(1);
      acc[0][0] = __builtin_amdgcn_mfma_f32_16x16x32_f16(b0, a0, acc[0][0], 0, 0, 0);
      acc[1][0] = __builtin_amdgcn_mfma_f32_16x16x32_f16(b0, a1, acc[1][0], 0, 0, 0);
      acc[0][1] = __builtin_amdgcn_mfma_f32_16x16x32_f16(b1, a0, acc[0][1], 0, 0, 0);
      acc[1][1] = __builtin_amdgcn_mfma_f32_16x16x32_f16(b1, a1, acc[1][1], 0, 0, 0);
      acc[0][2] = __builtin_amdgcn_mfma_f32_16x16x32_f16(b2, a0, acc[0][2], 0, 0, 0);
      acc[1][2] = __builtin_amdgcn_mfma_f32_16x16x32_f16(b2, a1, acc[1][2], 0, 0, 0);
      acc[0][3] = __builtin_amdgcn_mfma_f32_16x16x32_f16(b3, a0, acc[0][3], 0, 0, 0);
      acc[1][3] = __builtin_amdgcn_mfma_f32_16x16x32_f16(b3, a1, acc[1][3], 0, 0, 0);
      __builtin_amdgcn_s_setprio(0);
    }
  }
  __syncthreads();   // Q region dead beyond this point

  // prefetch PV sc=0 chunk0 KV2 frags; latency hides under softmax [T14]
  const unsigned short* KV2w = KV2 + (((size_t)(b * 8 + wv) * 16) << 12) + lane * 8;
  f16x8 v00 = *(const f16x8*)(KV2w);
  f16x8 v01 = *(const f16x8*)(KV2w + 512);
  f16x8 v02 = *(const f16x8*)(KV2w + 1024);
  f16x8 v03 = *(const f16x8*)(KV2w + 1536);

  // ---- softmax over KL ----
  float xlv[2], xmv[2];
#pragma unroll
  for (int m = 0; m < 2; ++m) {
    int row = m * 16 + l15;
    xlv[m] = xlg[row];
    xmv[m] = x_mask[(size_t)b * XL_ + x0 + row];
  }
  f32x4 klv[4], kmv[4];
#pragma unroll
  for (int n = 0; n < 4; ++n) {
    int kb = wv * 64 + n * 16 + l4 * 4;
    f32x4 s0 = *(const f32x4*)(klogP + (size_t)b * KL_ + kb);
    f32x4 s1 = *(const f32x4*)(klogP + (size_t)(B_ * KL_) + (size_t)b * KL_ + kb);
    f32x4 s2 = *(const f32x4*)(klogP + (size_t)(2 * B_ * KL_) + (size_t)b * KL_ + kb);
    f32x4 s3 = *(const f32x4*)(klogP + (size_t)(3 * B_ * KL_) + (size_t)b * KL_ + kb);
    klv[n] = (s0 + s1) + (s2 + s3);
    kmv[n] = *(const f32x4*)(key_mask + (size_t)b * KL_ + kb);
  }
  float mxsm[2] = {-3.0e38f, -3.0e38f}, mxs2[2] = {-3.0e38f, -3.0e38f};
#pragma unroll
  for (int m = 0; m < 2; ++m)
#pragma unroll
    for (int n = 0; n < 4; ++n)
#pragma unroll
      for (int q = 0; q < 4; ++q) {
        float s = acc[m][n][q] + xlv[m] + klv[n][q];
        float sm = s + (1.f - xmv[m] * kmv[n][q]) * NEGC;
        float s2 = s * kmv[n][q] + (1.f - kmv[n][q]) * NEGC;
        mxsm[m] = fmaxf(mxsm[m], sm);
        mxs2[m] = fmaxf(mxs2[m], s2);
      }
#pragma unroll
  for (int m = 0; m < 2; ++m) {
    mxsm[m] = fmaxf(mxsm[m], __shfl_xor(mxsm[m], 16));
    mxsm[m] = fmaxf(mxsm[m], __shfl_xor(mxsm[m], 32));
    mxs2[m] = fmaxf(mxs2[m], __shfl_xor(mxs2[m], 16));
    mxs2[m] = fmaxf(mxs2[m], __shfl_xor(mxs2[m], 32));
  }
  if (l4 == 0) {
#pragma unroll
    for (int m = 0; m < 2; ++m) {
      redA[wv * 32 + m * 16 + l15] = mxsm[m];
      redB[wv * 32 + m * 16 + l15] = mxs2[m];
    }
  }
  __syncthreads();
  float gmx[2];
#pragma unroll
  for (int m = 0; m < 2; ++m) {
    int row = m * 16 + l15;
    float v = redA[row];
#pragma unroll
    for (int w = 1; w < 8; ++w) v = fmaxf(v, redA[w * 32 + row]);
    gmx[m] = v;
  }
  if (tid < 32) {
    float v = redB[tid];
#pragma unroll
    for (int w = 1; w < 8; ++w) v = fmaxf(v, redB[w * 32 + tid]);
    maxs[(size_t)b * XL_ + x0 + tid] = v;
  }
  // exp pass: P^ written as [x-row][k] fp16, 8B granules, XOR-swizzled
  float rs[2] = {0.f, 0.f};
#pragma unroll
  for (int m = 0; m < 2; ++m) {
    int row = m * 16 + l15;
    char* prow = (char*)Pt + row * 1024;
    int rsw = row & 7;
#pragma unroll
    for (int n = 0; n < 4; ++n) {
      int k = wv * 64 + n * 16 + l4 * 4;
      u16x4 pk;
#pragma unroll
      for (int q = 0; q < 4; ++q) {
        float s = acc[m][n][q] + xlv[m] + klv[n][q];
        float sm = s + (1.f - xmv[m] * kmv[n][q]) * NEGC;
        float e = __expf(sm - gmx[m]);
        rs[m] += e;
        pk[q] = f2h(e);
      }
      *(u16x4*)(prow + ((((k >> 3) ^ rsw) << 4) + ((k & 4) << 1))) = pk;
    }
  }
#pragma unroll
  for (int m = 0; m < 2; ++m) {
    rs[m] += __shfl_xor(rs[m], 16);
    rs[m] += __shfl_xor(rs[m], 32);
  }
  if (l4 == 0) {
#pragma unroll
    for (int m = 0; m < 2; ++m) redC[wv * 32 + m * 16 + l15] = rs[m];
  }
  __syncthreads();

  // ---- PV: acc2[m][n] = mfma(KhTfrag_n, Pfrag_m), depth-2 rotation ----
  float dn[2];
#pragma unroll
  for (int m = 0; m < 2; ++m) {
    int row = m * 16 + l15;
    float sum = redC[row];
#pragma unroll
    for (int w = 1; w < 8; ++w) sum += redC[w * 32 + row];
    dn[m] = 1.f / sum;
  }
  size_t obase0 = ((size_t)b * XL_ + x0) * (size_t)(4 * D_);
  const char* pa0 = (char*)Pt + l15 * 1024;
  const char* pa1 = (char*)Pt + (16 + l15) * 1024;
#pragma unroll
  for (int sc = 0; sc < 2; ++sc) {
    int c0 = wv * 128 + sc * 64;
    f32x4 acc2[2][4];
#pragma unroll
    for (int m = 0; m < 2; ++m)
#pragma unroll
      for (int n = 0; n < 4; ++n) { f32x4 z = {0.f, 0.f, 0.f, 0.f}; acc2[m][n] = z; }
    const unsigned short* KV2s = KV2w + sc * 4 * 512;
    f16x8 q00, q01, q02, q03, q10, q11, q12, q13;
    if (sc == 0) { q00 = v00; q01 = v01; q02 = v02; q03 = v03; }
    else {
      q00 = *(const f16x8*)(KV2s);
      q01 = *(const f16x8*)(KV2s + 512);
      q02 = *(const f16x8*)(KV2s + 1024);
      q03 = *(const f16x8*)(KV2s + 1536);
    }
    q10 = *(const f16x8*)(KV2s + 4096);
    q11 = *(const f16x8*)(KV2s + 4096 + 512);
    q12 = *(const f16x8*)(KV2s + 4096 + 1024);
    q13 = *(const f16x8*)(KV2s + 4096 + 1536);
#pragma unroll 2
    for (int kk = 0; kk < KL_; kk += 64) {
      {
        f16x8 b0 = q00, b1 = q01, b2 = q02, b3 = q03;
        if (kk + 64 < KL_) {
          const unsigned short* cp = KV2s + (((kk + 64) >> 5) << 12);
          q00 = *(const f16x8*)(cp);
          q01 = *(const f16x8*)(cp + 512);
          q02 = *(const f16x8*)(cp + 1024);
          q03 = *(const f16x8*)(cp + 1536);
        }
        int c = ((((kk >> 3) + l4) ^ r7) << 4);
        f16x8 a0 = *(const f16x8*)(pa0 + c);
        f16x8 a1 = *(const f16x8*)(pa1 + c);
        __builtin_amdgcn_s_setprio(1);
        acc2[0][0] = __builtin_amdgcn_mfma_f32_16x16x32_f16(b0, a0, acc2[0][0], 0, 0, 0);
        acc2[1][0] = __builtin_amdgcn_mfma_f32_16x16x32_f16(b0, a1, acc2[1][0], 0, 0, 0);
        acc2[0][1] = __builtin_amdgcn_mfma_f32_16x16x32_f16(b1, a0, acc2[0][1], 0, 0, 0);
        acc2[1][1] = __builtin_amdgcn_mfma_f32_16x16x32_f16(b1, a1, acc2[1][1], 0, 0, 0);
        acc2[0][2] = __builtin_amdgcn_mfma_f32_16x16x32_f16(b2, a0, acc2[0][2], 0, 0, 0);
        acc2[1][2] = __builtin_amdgcn_mfma_f32_16x16x32_f16(b2, a1, acc2[1][2], 0, 0, 0);
        acc2[0][3] = __builtin_amdgcn_mfma_f32_16x16x32_f16(b3, a0, acc2[0][3], 0, 0, 0);
        acc2[1][3] = __builtin_amdgcn_mfma_f32_16x16x32_f16(b3, a1, acc2[1][3], 0, 0, 0);
        __builtin_amdgcn_s_setprio(0);
      }
      {
        int kk2 = kk + 32;
        f16x8 b0 = q10, b1 = q11, b2 = q12, b3 = q13;
        if (kk2 + 64 < KL_) {
          const unsigned short* cp = KV2s + (((kk2 + 64) >> 5) << 12);
          q10 = *(const f16x8*)(cp);
          q11 = *(const f16x8*)(cp + 512);
          q12 = *(const f16x8*)(cp + 1024);
          q13 = *(const f16x8*)(cp + 1536);
        }
        int c = ((((kk2 >> 3) + l4) ^ r7) << 4);
        f16x8 a0 = *(const f16x8*)(pa0 + c);
        f16x8 a1 = *(const f16x8*)(pa1 + c);
        __builtin_amdgcn_s_setprio(1);
        acc2[0][0] = __builtin_amdgcn_mfma_f32_16x16x32_f16(b0, a0, acc2[0][0], 0, 0, 0);
        acc2[1][0] = __builtin_amdgcn_mfma_f32_16x16x32_f16(b0, a1, acc2[1][0], 0, 0, 0);
        acc2[0][1] = __builtin_amdgcn_mfma_f32_16x16x32_f16(b1, a0, acc2[0][1], 0, 0, 0);
        acc2[1][1] = __builtin_amdgcn_mfma_f32_16x16x32_f16(b1, a1, acc2[1][1], 0, 0, 0);
        acc2[0][2] = __builtin_amdgcn_mfma_f32_16x16x32_f16(b2, a0, acc2[0][2], 0, 0, 0);
        acc2[1][2] = __builtin_amdgcn_mfma_f32_16x16x32_f16(b2, a1, acc2[1][2], 0, 0, 0);
        acc2[0][3] = __builtin_amdgcn_mfma_f32_16x16x32_f16(b3, a0, acc2[0][3], 0, 0, 0);
        acc2[1][3] = __builtin_amdgcn_mfma_f32_16x16x32_f16(b3, a1, acc2[1][3], 0, 0, 0);
        __builtin_amdgcn_s_setprio(0);
      }
    }
#pragma unroll
    for (int m = 0; m < 2; ++m) {
      int row = m * 16 + l15;
      size_t ob = obase0 + (size_t)row * (4 * D_);
#pragma unroll
      for (int n = 0; n < 4; ++n) {
        int col = c0 + n * 16 + l4 * 4;
        f32x4 v = acc2[m][n];
        v[0] *= dn[m]; v[1] *= dn[m]; v[2] *= dn[m]; v[3] *= dn[m];
        __builtin_nontemporal_store(v, (f32x4*)(out + ob + D_ + col));  // x2key only
      }
    }
  }
}

// ---------- key2x partials with fused p-softmax: block (b, xc) ----------
__global__ __launch_bounds__(256) void k_key2x_part(const float* __restrict__ x,
    const float* __restrict__ maxs, const float* __restrict__ x_mask,
    float* __restrict__ partial) {
  int b = blockIdx.x >> 4;
  int xc = blockIdx.x & 15;
  int tid = threadIdx.x;
  int wvi = tid >> 6, lane = tid & 63;
  __shared__ float r1[4], r2[4], r3[4];
  __shared__ float ps_all[XL_];
  const float* ms = maxs + (size_t)b * XL_;
  const float* xm = x_mask + (size_t)b * XL_;
  float tv[4], xmv[4];
  float vmax = -3.0e38f;
#pragma unroll
  for (int i = 0; i < 4; ++i) {
    int xi = i * 256 + tid;
    xmv[i] = xm[xi];
    tv[i] = ms[xi] * xmv[i];
    vmax = fmaxf(vmax, tv[i]);
  }
#pragma unroll
  for (int sh = 32; sh >= 1; sh >>= 1) vmax = fmaxf(vmax, __shfl_xor(vmax, sh));
  if (lane == 0) r1[wvi] = vmax;
  __syncthreads();
  float gmax = fmaxf(fmaxf(r1[0], r1[1]), fmaxf(r1[2], r1[3]));
  float e[4]; float es = 0.f;
#pragma unroll
  for (int i = 0; i < 4; ++i) { e[i] = __expf(tv[i] - gmax); es += e[i]; }
#pragma unroll
  for (int sh = 32; sh >= 1; sh >>= 1) es += __shfl_xor(es, sh);
  if (lane == 0) r2[wvi] = es;
  __syncthreads();
  float gsum = r2[0] + r2[1] + r2[2] + r2[3];
  float pv4[4]; float psum = 0.f;
#pragma unroll
  for (int i = 0; i < 4; ++i) { pv4[i] = e[i] / gsum * xmv[i]; psum += pv4[i]; }
#pragma unroll
  for (int sh = 32; sh >= 1; sh >>= 1) psum += __shfl_xor(psum, sh);
  if (lane == 0) r3[wvi] = psum;
  __syncthreads();
  float gps = r3[0] + r3[1] + r3[2] + r3[3];
  float inv = 1.f / (gps + 1e-13f);
#pragma unroll
  for (int i = 0; i < 4; ++i) ps_all[i * 256 + tid] = pv4[i] * inv;
  __syncthreads();
  const float* xb = x + ((size_t)b * XL_ + xc * 64) * D_;
  float acc0 = 0.f, acc1 = 0.f, acc2 = 0.f, acc3 = 0.f;
  int d = tid;
  const float* psl = ps_all + xc * 64;
  for (int xi = 0; xi < 64; ++xi) {
    float pv = psl[xi];
    const float* rp = xb + (size_t)xi * D_;
    acc0 += pv * __builtin_nontemporal_load(rp + d);
    acc1 += pv * __builtin_nontemporal_load(rp + d + 256);
    acc2 += pv * __builtin_nontemporal_load(rp + d + 512);
    acc3 += pv * __builtin_nontemporal_load(rp + d + 768);
  }
  float* pp = partial + (size_t)blockIdx.x * D_;
  pp[d] = acc0; pp[d + 256] = acc1; pp[d + 512] = acc2; pp[d + 768] = acc3;
}

// ---------- key2x reduce: k2x[b][d] = sum_xc partial ----------
__global__ __launch_bounds__(256) void k_key2x_red(const float* __restrict__ partial,
    float* __restrict__ k2x) {
  int idx = blockIdx.x * 256 + threadIdx.x;
  int b = idx >> 10;
  float s = 0.f;
#pragma unroll
  for (int xc = 0; xc < 16; ++xc)
    s += partial[((size_t)b * 16 + xc) * D_ + (idx & 1023)];
  k2x[idx] = s;
}

// ---------- streaming tail: out0 = x, out2 = x*x2key, out3 = x*key2x ----------
__global__ __launch_bounds__(256) void k_mega(const float* __restrict__ x,
    const float* __restrict__ k2x, float* __restrict__ out) {
  size_t t = (size_t)blockIdx.x * 256 + threadIdx.x;
  size_t base = t * 4;
  int b = (int)(base >> 20);
  int rem = (int)(base & ((1u << 20) - 1));
  int xr = rem >> 10;
  int d = rem & 1023;
  f32x4 xv = __builtin_nontemporal_load((const f32x4*)(x + base));
  f32x4 kv = *(const f32x4*)(k2x + (size_t)b * D_ + d);
  float* orow = out + ((size_t)b * XL_ + xr) * (size_t)(4 * D_);
  f32x4 x2 = __builtin_nontemporal_load((const f32x4*)(orow + D_ + d));
  __builtin_nontemporal_store(xv, (f32x4*)(orow + d));              // x
  f32x4 p2;
  p2[0] = xv[0] * x2[0]; p2[1] = xv[1] * x2[1];
  p2[2] = xv[2] * x2[2]; p2[3] = xv[3] * x2[3];
  __builtin_nontemporal_store(p2, (f32x4*)(orow + 2 * D_ + d));     // x * x2key
  f32x4 p3;
  p3[0] = xv[0] * kv[0]; p3[1] = xv[1] * kv[1];
  p3[2] = xv[2] * kv[2]; p3[3] = xv[3] * kv[3];
  __builtin_nontemporal_store(p3, (f32x4*)(orow + 3 * D_ + d));     // x * key2x
}

extern "C" void kernel_launch(void* const* d_in, const int* in_sizes, int n_in,
                              void* d_out, int out_size, void* d_ws, size_t ws_size,
                              hipStream_t stream) {
  (void)in_sizes; (void)n_in; (void)out_size; (void)ws_size;
  const float* x        = (const float*)d_in[0];
  const float* x_mask   = (const float*)d_in[1];
  const float* key      = (const float*)d_in[2];
  const float* key_mask = (const float*)d_in[3];
  const float* w_input  = (const float*)d_in[4];
  const float* w_key    = (const float*)d_in[5];
  const float* dot_w    = (const float*)d_in[6];
  float* out = (float*)d_out;
  char* ws = (char*)d_ws;

  unsigned short* KQ2 = (unsigned short*)ws;                        // 16 MB
  unsigned short* KV2 = (unsigned short*)(ws + (16u << 20));        // 16 MB
  float* klogP = (float*)(ws + (32u << 20));                        // 4x32 KB planes
  float* maxs = klogP + 4 * B_ * KL_;                               // 64 KB
  float* k2x  = maxs + B_ * XL_;                                    // 64 KB
  float* partial = (float*)ws;   // 1 MB, aliases KQ2 (dead after k_attn)

  k_build<<<dim3(B_ * 32), dim3(256), 0, stream>>>(key, w_key, KQ2, KV2, klogP);
  k_attn<<<dim3(512), dim3(512), 0, stream>>>(x, x_mask, key_mask, dot_w, w_input,
                                              KQ2, KV2, klogP, maxs, out);
  k_key2x_part<<<dim3(B_ * 16), dim3(256), 0, stream>>>(x, maxs, x_mask, partial);
  k_key2x_red<<<dim3(B_ * D_ / 256), dim3(256), 0, stream>>>(partial, k2x);
  k_mega<<<dim3(B_ * XL_ * D_ / 1024), dim3(256), 0, stream>>>(x, k2x, out);
}